// Round 2
// baseline (439.620 us; speedup 1.0000x reference)
//
#include <hip/hip_runtime.h>

typedef _Float16 f16;
typedef float f32x4 __attribute__((ext_vector_type(4)));
typedef _Float16 f16x8 __attribute__((ext_vector_type(8)));
typedef _Float16 f16x4 __attribute__((ext_vector_type(4)));

#define MFMA16(a, b, c) __builtin_amdgcn_mfma_f32_16x16x32_f16((a), (b), (c), 0, 0, 0)

__device__ __forceinline__ void gld16(const void* g, void* l) {
    __builtin_amdgcn_global_load_lds((const __attribute__((address_space(1))) unsigned int*)g,
                                     (__attribute__((address_space(3))) unsigned int*)l, 16, 0, 0);
}

// ---------------- fp32 -> fp16 cast (8 elems/thread) ----------------
__global__ __launch_bounds__(256) void cvt_f32_f16(const float* __restrict__ src,
                                                   f16* __restrict__ dst, int n) {
    int i = (blockIdx.x * 256 + threadIdx.x) * 8;
    if (i >= n) return;
    float4 a = *(const float4*)(src + i);
    float4 b = *(const float4*)(src + i + 4);
    f16x8 o;
    o[0] = (f16)a.x; o[1] = (f16)a.y; o[2] = (f16)a.z; o[3] = (f16)a.w;
    o[4] = (f16)b.x; o[5] = (f16)b.y; o[6] = (f16)b.z; o[7] = (f16)b.w;
    *(f16x8*)(dst + i) = o;
}

// ---------------- GEMM: C[M,N] = A[M,K] * W[N,K]^T  (f16 in, f32 out) -------
// 128x128 tile, BK=32, 256 threads (4 waves in 2x2), m97 structure.
__global__ __launch_bounds__(256) void gemm_bt(const f16* __restrict__ A, const f16* __restrict__ W,
                                               float* __restrict__ C, int M, int N, int K) {
    __shared__ __align__(16) f16 As[128 * 32];
    __shared__ __align__(16) f16 Bs[128 * 32];
    const int tid = threadIdx.x;
    const int lane = tid & 63, wid = tid >> 6;
    const int wr = wid >> 1, wc = wid & 1;
    const int m0 = blockIdx.y * 128, n0 = blockIdx.x * 128;
    f32x4 acc[4][4] = {};

    const int off0 = wid * 1024 + lane * 16;      // byte offset in 8KB tile, issue 0
    const int off1 = off0 + 4096;                 // issue 1
    const int r0 = off0 >> 6, kc0 = (off0 & 63) >> 1;
    const int r1 = off1 >> 6, kc1 = (off1 & 63) >> 1;
    const f16* a0p = A + (size_t)(m0 + r0) * K + kc0;
    const f16* a1p = A + (size_t)(m0 + r1) * K + kc1;
    const f16* b0p = W + (size_t)(n0 + r0) * K + kc0;
    const f16* b1p = W + (size_t)(n0 + r1) * K + kc1;
    char* asb = (char*)As;
    char* bsb = (char*)Bs;

    for (int k0 = 0; k0 < K; k0 += 32) {
        gld16(a0p + k0, asb + wid * 1024);
        gld16(a1p + k0, asb + 4096 + wid * 1024);
        gld16(b0p + k0, bsb + wid * 1024);
        gld16(b1p + k0, bsb + 4096 + wid * 1024);
        __syncthreads();
        f16x8 af[4], bfr[4];
#pragma unroll
        for (int m = 0; m < 4; ++m)
            af[m] = *(const f16x8*)(asb + ((wr * 64 + m * 16 + (lane & 15)) * 32 + (lane >> 4) * 8) * 2);
#pragma unroll
        for (int n = 0; n < 4; ++n)
            bfr[n] = *(const f16x8*)(bsb + ((wc * 64 + n * 16 + (lane & 15)) * 32 + (lane >> 4) * 8) * 2);
#pragma unroll
        for (int m = 0; m < 4; ++m)
#pragma unroll
            for (int n = 0; n < 4; ++n)
                acc[m][n] = MFMA16(af[m], bfr[n], acc[m][n]);
        __syncthreads();
    }
#pragma unroll
    for (int m = 0; m < 4; ++m) {
        int row = m0 + wr * 64 + m * 16 + ((lane >> 4) << 2);
#pragma unroll
        for (int n = 0; n < 4; ++n) {
            int col = n0 + wc * 64 + n * 16 + (lane & 15);
#pragma unroll
            for (int r = 0; r < 4; ++r)
                C[(size_t)(row + r) * N + col] = acc[m][n][r];
        }
    }
}

// ---------------- RMSNorm + RoPE for q and k; one wave per (b,s,head) -------
// qkv layout: [B*S][4096] = [q(8*256) | k(4*256) | v(4*256)]
__global__ __launch_bounds__(256) void rmsrope_k(const float* __restrict__ qkv,
                                                 const float* __restrict__ cosb, const float* __restrict__ sinb,
                                                 const float* __restrict__ qnw, const float* __restrict__ knw,
                                                 f16* __restrict__ qr, f16* __restrict__ kr) {
    int wid = threadIdx.x >> 6, lane = threadIdx.x & 63;
    int task = blockIdx.x * 4 + wid;           // < B*S*12
    int slot = task % 12;
    int bs = task / 12;                        // b*2048 + s
    int b = bs >> 11, s = bs & 2047;
    const float* src;
    const float* w;
    f16* dst;
    if (slot < 8) {
        src = qkv + (size_t)bs * 4096 + slot * 256;
        w = qnw;
        dst = qr + ((size_t)(b * 8 + slot) * 2048 + s) * 256;
    } else {
        int h = slot - 8;
        src = qkv + (size_t)bs * 4096 + 2048 + h * 256;
        w = knw;
        dst = kr + ((size_t)(b * 4 + h) * 2048 + s) * 256;
    }
    int i = lane * 4;
    float4 x = *(const float4*)(src + i);
    float ss = x.x * x.x + x.y * x.y + x.z * x.z + x.w * x.w;
#pragma unroll
    for (int o = 32; o; o >>= 1) ss += __shfl_xor(ss, o, 64);
    float rs = rsqrtf(ss * (1.0f / 256.0f) + 1e-6f);
    float4 y;
    y.x = __shfl_xor(x.x, 32, 64);
    y.y = __shfl_xor(x.y, 32, 64);
    y.z = __shfl_xor(x.z, 32, 64);
    y.w = __shfl_xor(x.w, 32, 64);
    float4 wv = *(const float4*)(w + i);
    float4 wp = *(const float4*)(w + (i ^ 128));
    float4 c = *(const float4*)(cosb + (size_t)bs * 256 + i);
    float4 sn = *(const float4*)(sinb + (size_t)bs * 256 + i);
    float sgn = (lane < 32) ? -1.0f : 1.0f;
    float n0 = x.x * rs * (1.f + wv.x), n1 = x.y * rs * (1.f + wv.y);
    float n2 = x.z * rs * (1.f + wv.z), n3 = x.w * rs * (1.f + wv.w);
    float r0 = y.x * rs * (1.f + wp.x) * sgn, r1 = y.y * rs * (1.f + wp.y) * sgn;
    float r2 = y.z * rs * (1.f + wp.z) * sgn, r3 = y.w * rs * (1.f + wp.w) * sgn;
    float o0 = n0 * c.x + r0 * sn.x;
    float o1 = n1 * c.y + r1 * sn.y;
    float o2 = n2 * c.z + r2 * sn.z;
    float o3 = n3 * c.w + r3 * sn.w;
    f16x4 outv;
    outv[0] = (f16)o0; outv[1] = (f16)o1; outv[2] = (f16)o2; outv[3] = (f16)o3;
    *(f16x4*)(dst + i) = outv;
}

// ---------------- V: cast + transpose -> vt[b][kvh][d][s] (f16) -------------
__global__ __launch_bounds__(256) void vtrans_k(const float* __restrict__ qkv, f16* __restrict__ vt) {
    int g = blockIdx.x * 256 + threadIdx.x;    // total = 2*4*256*512 = 1,048,576
    int s4 = g & 511;
    int d = (g >> 9) & 255;
    int kvh = (g >> 17) & 3;
    int b = g >> 19;
    int s = s4 * 4;
    size_t src = ((size_t)(b * 2048 + s)) * 4096 + 3072 + kvh * 256 + d;
    float v0 = qkv[src];
    float v1 = qkv[src + 4096];
    float v2 = qkv[src + 2 * 4096];
    float v3 = qkv[src + 3 * 4096];
    f16x4 o;
    o[0] = (f16)v0; o[1] = (f16)v1; o[2] = (f16)v2; o[3] = (f16)v3;
    *(f16x4*)(vt + ((size_t)((b * 4 + kvh) * 256 + d) * 2048 + s)) = o;
}

// ---------------- scores: raw softcapped+masked scores into probs buffer ----
// grid (9, 32, 16): x = rel k-tile, y = q-tile, z = b*8+h
__global__ __launch_bounds__(256) void scores_k(const f16* __restrict__ qr, const f16* __restrict__ kr,
                                                float* __restrict__ probs) {
    int qt = blockIdx.y;
    int bh = blockIdx.z;
    int kt = qt - 8 + (int)blockIdx.x;
    if (kt < 0) return;
    int b = bh >> 3, h = bh & 7;
    __shared__ __align__(16) f16 Ks[64 * 256];
    int tid = threadIdx.x, lane = tid & 63, wid = tid >> 6;
    const f16* kbase = kr + ((size_t)((b * 4 + (h >> 1)) * 2048) + kt * 64) * 256;
    char* ksb = (char*)Ks;
#pragma unroll
    for (int is = 0; is < 8; ++is) {
        int off = is * 4096 + wid * 1024 + lane * 16;
        int row = off >> 9;
        int ke = (off & 511) >> 1;
        gld16(kbase + (size_t)row * 256 + ke, ksb + is * 4096 + wid * 1024);
    }
    const f16* qbase = qr + ((size_t)bh * 2048 + qt * 64) * 256;
    f16x8 af[8];
#pragma unroll
    for (int ks = 0; ks < 8; ++ks)
        af[ks] = *(const f16x8*)(qbase + (size_t)(wid * 16 + (lane & 15)) * 256 + ks * 32 + (lane >> 4) * 8);
    __syncthreads();
    f32x4 acc[4] = {};
#pragma unroll
    for (int n = 0; n < 4; ++n)
#pragma unroll
        for (int ks = 0; ks < 8; ++ks) {
            f16x8 bfr = *(const f16x8*)(ksb + ((n * 16 + (lane & 15)) * 256 + ks * 32 + (lane >> 4) * 8) * 2);
            acc[n] = MFMA16(af[ks], bfr, acc[n]);
        }
#pragma unroll
    for (int n = 0; n < 4; ++n) {
        int col = kt * 64 + n * 16 + (lane & 15);
#pragma unroll
        for (int r = 0; r < 4; ++r) {
            int row = qt * 64 + wid * 16 + ((lane >> 4) << 2) + r;
            float v = acc[n][r] * 0.0625f;      // * 256^-0.5
            v = 50.0f * tanhf(v * 0.02f);       // softcap
            bool ok = (col <= row) && ((row - col) < 512);
            probs[((size_t)bh * 2048 + row) * 2048 + col] = ok ? v : -1e9f;
        }
    }
}

// ---------------- softmax: normalize band + write zeros outside band --------
// One wave per row. Writes the ENTIRE 2048-wide row (replaces the memset).
__global__ __launch_bounds__(256) void softmax_k(float* __restrict__ probs) {
    int wid = threadIdx.x >> 6, lane = threadIdx.x & 63;
    int task = blockIdx.x * 4 + wid;           // < 32768
    int i = task & 2047;
    int bh = task >> 11;
    int qt = i >> 6;
    int kt0 = qt > 8 ? qt - 8 : 0;
    int col0 = kt0 * 64;
    int nt = qt - kt0 + 1;                     // <= 9
    float* row = probs + ((size_t)bh * 2048 + i) * 2048;
    float s[9];
    float m = -1e30f;
#pragma unroll
    for (int t = 0; t < 9; ++t) {
        s[t] = (t < nt) ? row[col0 + t * 64 + lane] : -1e30f;
        m = fmaxf(m, s[t]);
    }
#pragma unroll
    for (int o = 32; o; o >>= 1) m = fmaxf(m, __shfl_xor(m, o, 64));
    float sum = 0.f;
#pragma unroll
    for (int t = 0; t < 9; ++t) {
        s[t] = __expf(s[t] - m);
        sum += s[t];
    }
#pragma unroll
    for (int o = 32; o; o >>= 1) sum += __shfl_xor(sum, o, 64);
    float inv = 1.0f / sum;
    // band (static register indices — rule #20)
#pragma unroll
    for (int t = 0; t < 9; ++t)
        if (t < nt) row[col0 + t * 64 + lane] = s[t] * inv;
    // zeros outside band, float4-vectorized (wave covers 1KB per iter)
    float4 z4 = make_float4(0.f, 0.f, 0.f, 0.f);
    for (int off = lane * 4; off < col0; off += 256)
        *(float4*)(row + off) = z4;
    for (int off = (qt + 1) * 64 + lane * 4; off < 2048; off += 256)
        *(float4*)(row + off) = z4;
}

// ---------------- PV: attn[b][s][h*256+d] = probs @ V ----------------------
// grid (32, 16): x = q-tile, y = b*8+h
__global__ __launch_bounds__(256) void pv_k(const float* __restrict__ probs, const f16* __restrict__ vt,
                                            f16* __restrict__ attn) {
    int qt = blockIdx.x, bh = blockIdx.y;
    int b = bh >> 3, h = bh & 7;
    __shared__ __align__(16) f16 Vs[256 * 64];   // [d][key]
    int tid = threadIdx.x, lane = tid & 63, wid = tid >> 6;
    int kt0 = qt > 8 ? qt - 8 : 0;
    const f16* vtb = vt + (size_t)((b * 4 + (h >> 1)) * 256) * 2048;
    char* vsb = (char*)Vs;
    f32x4 acc[16] = {};
    const float* prow0 = probs + ((size_t)bh * 2048 + qt * 64 + wid * 16 + (lane & 15)) * 2048 + (lane >> 4) * 8;
    for (int kt = kt0; kt <= qt; ++kt) {
#pragma unroll
        for (int is = 0; is < 8; ++is) {
            int off = is * 4096 + wid * 1024 + lane * 16;
            int d = off >> 7;
            int ke = (off & 127) >> 1;
            gld16(vtb + (size_t)d * 2048 + kt * 64 + ke, vsb + is * 4096 + wid * 1024);
        }
        const float* pr = prow0 + kt * 64;
        float4 xa = *(const float4*)(pr);
        float4 xb = *(const float4*)(pr + 4);
        float4 xc = *(const float4*)(pr + 32);
        float4 xd = *(const float4*)(pr + 36);
        f16x8 a0, a1;
        a0[0] = (f16)xa.x; a0[1] = (f16)xa.y; a0[2] = (f16)xa.z; a0[3] = (f16)xa.w;
        a0[4] = (f16)xb.x; a0[5] = (f16)xb.y; a0[6] = (f16)xb.z; a0[7] = (f16)xb.w;
        a1[0] = (f16)xc.x; a1[1] = (f16)xc.y; a1[2] = (f16)xc.z; a1[3] = (f16)xc.w;
        a1[4] = (f16)xd.x; a1[5] = (f16)xd.y; a1[6] = (f16)xd.z; a1[7] = (f16)xd.w;
        __syncthreads();
#pragma unroll
        for (int n = 0; n < 16; ++n) {
            f16x8 b0 = *(const f16x8*)(vsb + ((n * 16 + (lane & 15)) * 64 + (lane >> 4) * 8) * 2);
            f16x8 b1 = *(const f16x8*)(vsb + ((n * 16 + (lane & 15)) * 64 + 32 + (lane >> 4) * 8) * 2);
            acc[n] = MFMA16(a0, b0, acc[n]);
            acc[n] = MFMA16(a1, b1, acc[n]);
        }
        __syncthreads();
    }
    size_t obase = ((size_t)b * 2048 + qt * 64 + wid * 16 + ((lane >> 4) << 2)) * 2048 + h * 256;
#pragma unroll
    for (int n = 0; n < 16; ++n) {
        int col = n * 16 + (lane & 15);
#pragma unroll
        for (int r = 0; r < 4; ++r)
            attn[obase + (size_t)r * 2048 + col] = (f16)acc[n][r];
    }
}

extern "C" void kernel_launch(void* const* d_in, const int* in_sizes, int n_in,
                              void* d_out, int out_size, void* d_ws, size_t ws_size,
                              hipStream_t stream) {
    (void)in_sizes; (void)n_in; (void)out_size; (void)ws_size;
    const float* hs   = (const float*)d_in[0];
    const float* cosb = (const float*)d_in[1];
    const float* sinb = (const float*)d_in[2];
    const float* qw   = (const float*)d_in[4];
    const float* kw   = (const float*)d_in[5];
    const float* vw   = (const float*)d_in[6];
    const float* ow   = (const float*)d_in[7];
    const float* qnw  = (const float*)d_in[8];
    const float* knw  = (const float*)d_in[9];

    float* out = (float*)d_out;
    float* probs = out + (size_t)2 * 2048 * 2560;          // output 1

    char* ws = (char*)d_ws;
    f16* hsb    = (f16*)(ws);                              // 20,971,520 B
    f16* wqkv   = (f16*)(ws + 20971520);                   // 20,971,520 B
    f16* owb    = (f16*)(ws + 41943040);                   // 10,485,760 B
    float* qkvf = (float*)(ws + 52428800);                 // 67,108,864 B
    f16* qr     = (f16*)(ws + 119537664);                  // 16,777,216 B
    f16* kr     = (f16*)(ws + 136314880);                  //  8,388,608 B
    f16* vt     = (f16*)(ws + 144703488);                  //  8,388,608 B
    f16* attn   = (f16*)(ws + 153092096);                  // 16,777,216 B -> total 169,869,312 B

    // fp32 -> fp16 casts
    cvt_f32_f16<<<5120, 256, 0, stream>>>(hs, hsb, 10485760);
    cvt_f32_f16<<<2560, 256, 0, stream>>>(qw, wqkv, 5242880);
    cvt_f32_f16<<<1280, 256, 0, stream>>>(kw, wqkv + 5242880, 2621440);
    cvt_f32_f16<<<1280, 256, 0, stream>>>(vw, wqkv + 7864320, 2621440);
    cvt_f32_f16<<<2560, 256, 0, stream>>>(ow, owb, 5242880);

    // fused QKV projection: [4096, 2560] x [4096, 2560]^T -> [4096, 4096] fp32
    gemm_bt<<<dim3(32, 32), 256, 0, stream>>>(hsb, wqkv, qkvf, 4096, 4096, 2560);

    // RMSNorm + RoPE -> qr [B,H,S,256], kr [B,KVH,S,256]; V transpose -> vt [B,KVH,256,S]
    rmsrope_k<<<12288, 256, 0, stream>>>(qkvf, cosb, sinb, qnw, knw, qr, kr);
    vtrans_k<<<4096, 256, 0, stream>>>(qkvf, vt);

    // scores into band, then softmax writes FULL probs rows (no memset needed)
    scores_k<<<dim3(9, 32, 16), 256, 0, stream>>>(qr, kr, probs);
    softmax_k<<<8192, 256, 0, stream>>>(probs);

    // PV -> attn [B,S,H*256] f16
    pv_k<<<dim3(32, 16), 256, 0, stream>>>(probs, vt, attn);

    // O projection: [4096, 2048] x [2560, 2048]^T -> [4096, 2560] fp32 (output 0)
    gemm_bt<<<dim3(20, 32), 256, 0, stream>>>(attn, owb, out, 4096, 2560, 2048);
}

// Round 3
// 433.615 us; speedup vs baseline: 1.0139x; 1.0139x over previous
//
#include <hip/hip_runtime.h>

typedef _Float16 f16;
typedef float f32x4 __attribute__((ext_vector_type(4)));
typedef _Float16 f16x8 __attribute__((ext_vector_type(8)));
typedef _Float16 f16x4 __attribute__((ext_vector_type(4)));
typedef _Float16 f16x2 __attribute__((ext_vector_type(2)));

#define MFMA16(a, b, c) __builtin_amdgcn_mfma_f32_16x16x32_f16((a), (b), (c), 0, 0, 0)

__device__ __forceinline__ void gld16(const void* g, void* l) {
    __builtin_amdgcn_global_load_lds((const __attribute__((address_space(1))) unsigned int*)g,
                                     (__attribute__((address_space(3))) unsigned int*)l, 16, 0, 0);
}

// ---------------- fp32 -> fp16 cast (8 elems/thread) ----------------
__global__ __launch_bounds__(256) void cvt_f32_f16(const float* __restrict__ src,
                                                   f16* __restrict__ dst, int n) {
    int i = (blockIdx.x * 256 + threadIdx.x) * 8;
    if (i >= n) return;
    float4 a = *(const float4*)(src + i);
    float4 b = *(const float4*)(src + i + 4);
    f16x8 o;
    o[0] = (f16)a.x; o[1] = (f16)a.y; o[2] = (f16)a.z; o[3] = (f16)a.w;
    o[4] = (f16)b.x; o[5] = (f16)b.y; o[6] = (f16)b.z; o[7] = (f16)b.w;
    *(f16x8*)(dst + i) = o;
}

// ---------------- GEMM: C[M,N] = A[M,K] * W[N,K]^T  (f16 in, f32 out) -------
__global__ __launch_bounds__(256) void gemm_bt(const f16* __restrict__ A, const f16* __restrict__ W,
                                               float* __restrict__ C, int M, int N, int K) {
    __shared__ __align__(16) f16 As[128 * 32];
    __shared__ __align__(16) f16 Bs[128 * 32];
    const int tid = threadIdx.x;
    const int lane = tid & 63, wid = tid >> 6;
    const int wr = wid >> 1, wc = wid & 1;
    const int m0 = blockIdx.y * 128, n0 = blockIdx.x * 128;
    f32x4 acc[4][4] = {};

    const int off0 = wid * 1024 + lane * 16;
    const int off1 = off0 + 4096;
    const int r0 = off0 >> 6, kc0 = (off0 & 63) >> 1;
    const int r1 = off1 >> 6, kc1 = (off1 & 63) >> 1;
    const f16* a0p = A + (size_t)(m0 + r0) * K + kc0;
    const f16* a1p = A + (size_t)(m0 + r1) * K + kc1;
    const f16* b0p = W + (size_t)(n0 + r0) * K + kc0;
    const f16* b1p = W + (size_t)(n0 + r1) * K + kc1;
    char* asb = (char*)As;
    char* bsb = (char*)Bs;

    for (int k0 = 0; k0 < K; k0 += 32) {
        gld16(a0p + k0, asb + wid * 1024);
        gld16(a1p + k0, asb + 4096 + wid * 1024);
        gld16(b0p + k0, bsb + wid * 1024);
        gld16(b1p + k0, bsb + 4096 + wid * 1024);
        __syncthreads();
        f16x8 af[4], bfr[4];
#pragma unroll
        for (int m = 0; m < 4; ++m)
            af[m] = *(const f16x8*)(asb + ((wr * 64 + m * 16 + (lane & 15)) * 32 + (lane >> 4) * 8) * 2);
#pragma unroll
        for (int n = 0; n < 4; ++n)
            bfr[n] = *(const f16x8*)(bsb + ((wc * 64 + n * 16 + (lane & 15)) * 32 + (lane >> 4) * 8) * 2);
#pragma unroll
        for (int m = 0; m < 4; ++m)
#pragma unroll
            for (int n = 0; n < 4; ++n)
                acc[m][n] = MFMA16(af[m], bfr[n], acc[m][n]);
        __syncthreads();
    }
#pragma unroll
    for (int m = 0; m < 4; ++m) {
        int row = m0 + wr * 64 + m * 16 + ((lane >> 4) << 2);
#pragma unroll
        for (int n = 0; n < 4; ++n) {
            int col = n0 + wc * 64 + n * 16 + (lane & 15);
#pragma unroll
            for (int r = 0; r < 4; ++r)
                C[(size_t)(row + r) * N + col] = acc[m][n][r];
        }
    }
}

// ---------------- RMSNorm + RoPE for q and k; one wave per (b,s,head) -------
__global__ __launch_bounds__(256) void rmsrope_k(const float* __restrict__ qkv,
                                                 const float* __restrict__ cosb, const float* __restrict__ sinb,
                                                 const float* __restrict__ qnw, const float* __restrict__ knw,
                                                 f16* __restrict__ qr, f16* __restrict__ kr) {
    int wid = threadIdx.x >> 6, lane = threadIdx.x & 63;
    int task = blockIdx.x * 4 + wid;           // < B*S*12
    int slot = task % 12;
    int bs = task / 12;
    int b = bs >> 11, s = bs & 2047;
    const float* src;
    const float* w;
    f16* dst;
    if (slot < 8) {
        src = qkv + (size_t)bs * 4096 + slot * 256;
        w = qnw;
        dst = qr + ((size_t)(b * 8 + slot) * 2048 + s) * 256;
    } else {
        int h = slot - 8;
        src = qkv + (size_t)bs * 4096 + 2048 + h * 256;
        w = knw;
        dst = kr + ((size_t)(b * 4 + h) * 2048 + s) * 256;
    }
    int i = lane * 4;
    float4 x = *(const float4*)(src + i);
    float ss = x.x * x.x + x.y * x.y + x.z * x.z + x.w * x.w;
#pragma unroll
    for (int o = 32; o; o >>= 1) ss += __shfl_xor(ss, o, 64);
    float rs = rsqrtf(ss * (1.0f / 256.0f) + 1e-6f);
    float4 y;
    y.x = __shfl_xor(x.x, 32, 64);
    y.y = __shfl_xor(x.y, 32, 64);
    y.z = __shfl_xor(x.z, 32, 64);
    y.w = __shfl_xor(x.w, 32, 64);
    float4 wv = *(const float4*)(w + i);
    float4 wp = *(const float4*)(w + (i ^ 128));
    float4 c = *(const float4*)(cosb + (size_t)bs * 256 + i);
    float4 sn = *(const float4*)(sinb + (size_t)bs * 256 + i);
    float sgn = (lane < 32) ? -1.0f : 1.0f;
    float n0 = x.x * rs * (1.f + wv.x), n1 = x.y * rs * (1.f + wv.y);
    float n2 = x.z * rs * (1.f + wv.z), n3 = x.w * rs * (1.f + wv.w);
    float r0 = y.x * rs * (1.f + wp.x) * sgn, r1 = y.y * rs * (1.f + wp.y) * sgn;
    float r2 = y.z * rs * (1.f + wp.z) * sgn, r3 = y.w * rs * (1.f + wp.w) * sgn;
    float o0 = n0 * c.x + r0 * sn.x;
    float o1 = n1 * c.y + r1 * sn.y;
    float o2 = n2 * c.z + r2 * sn.z;
    float o3 = n3 * c.w + r3 * sn.w;
    f16x4 outv;
    outv[0] = (f16)o0; outv[1] = (f16)o1; outv[2] = (f16)o2; outv[3] = (f16)o3;
    *(f16x4*)(dst + i) = outv;
}

// ---------------- V: cast + transpose via LDS -> vt[b][kvh][d][s] (f16) -----
// Tile: 64 s x 256 d. Coalesced reads, padded-LDS transpose, 128B-chunk writes.
__global__ __launch_bounds__(256) void vtrans2(const float* __restrict__ qkv, f16* __restrict__ vt) {
    __shared__ __align__(16) char Ls[64 * 516];   // 64 rows of (258 f16 = 516 B)
    int tile = blockIdx.x;           // 0..255
    int st = tile & 31;              // s-tile
    int by = tile >> 5;              // b*4 + kvh
    int b = by >> 2, kvh = by & 3;
    int tid = threadIdx.x;
    int s0 = st * 64;
    const float* src = qkv + ((size_t)(b * 2048 + s0)) * 4096 + 3072 + kvh * 256;
#pragma unroll
    for (int it = 0; it < 16; ++it) {
        int idx = it * 256 + tid;
        int srow = idx >> 6;
        int col = (idx & 63) * 4;
        float4 x = *(const float4*)(src + (size_t)srow * 4096 + col);
        f16x2 lo, hi;
        lo[0] = (f16)x.x; lo[1] = (f16)x.y;
        hi[0] = (f16)x.z; hi[1] = (f16)x.w;
        *(f16x2*)(Ls + srow * 516 + col * 2) = lo;
        *(f16x2*)(Ls + srow * 516 + col * 2 + 4) = hi;
    }
    __syncthreads();
    f16* dst = vt + ((size_t)(by * 256) * 2048) + s0;
#pragma unroll
    for (int p = 0; p < 8; ++p) {
        int d = p * 32 + (tid >> 3);
        int s8 = (tid & 7) * 8;
        f16x8 o;
#pragma unroll
        for (int j = 0; j < 8; ++j)
            o[j] = *(const f16*)(Ls + (s8 + j) * 516 + d * 2);
        *(f16x8*)(dst + (size_t)d * 2048 + s8) = o;
    }
}

// ------------- fused scores + softcap + mask + softmax -> probs -------------
// grid (32 qt, 16 bh), 4 waves; wave w owns q-rows [qt*64+w*16, +16).
// Band of 9 k-tiles kept in registers (acc[9][4], statically indexed).
__global__ __launch_bounds__(256) void sscore_k(const f16* __restrict__ qr, const f16* __restrict__ kr,
                                                float* __restrict__ probs) {
    int qt = blockIdx.x, bh = blockIdx.y;
    int b = bh >> 3, h = bh & 7;
    int tid = threadIdx.x, lane = tid & 63, w = tid >> 6;
    __shared__ __align__(16) f16 Ks[64 * 256];
    char* ksb = (char*)Ks;

    // Q fragments for this wave's 16 rows (read once)
    const f16* qbase = qr + ((size_t)bh * 2048 + qt * 64 + w * 16 + (lane & 15)) * 256 + (lane >> 4) * 8;
    f16x8 af[8];
#pragma unroll
    for (int ks = 0; ks < 8; ++ks) af[ks] = *(const f16x8*)(qbase + ks * 32);

    f32x4 acc[9][4] = {};
    const f16* kb0 = kr + ((size_t)((b * 4 + (h >> 1)) * 2048)) * 256;
#pragma unroll
    for (int kt = 0; kt < 9; ++kt) {
        int kta = qt - 8 + kt;
        if (kta >= 0) {                          // block-uniform
            const f16* kbase = kb0 + (size_t)kta * 64 * 256;
#pragma unroll
            for (int is = 0; is < 8; ++is) {
                int off = is * 4096 + w * 1024 + lane * 16;
                int row = off >> 9;
                int ke = (off & 511) >> 1;
                gld16(kbase + (size_t)row * 256 + ke, ksb + is * 4096 + w * 1024);
            }
            __syncthreads();
#pragma unroll
            for (int n = 0; n < 4; ++n)
#pragma unroll
                for (int ks = 0; ks < 8; ++ks) {
                    f16x8 bfr = *(const f16x8*)(ksb + ((n * 16 + (lane & 15)) * 256 + ks * 32 + (lane >> 4) * 8) * 2);
                    acc[kt][n] = MFMA16(af[ks], bfr, acc[kt][n]);
                }
            __syncthreads();
        }
    }

    // softcap + mask, track row max (rows: row_g0 + r, r=0..3)
    int row_l = w * 16 + ((lane >> 4) << 2);
    int row_g0 = qt * 64 + row_l;
    f32x4 mx = {-1e30f, -1e30f, -1e30f, -1e30f};
#pragma unroll
    for (int kt = 0; kt < 9; ++kt) {
        int kta = qt - 8 + kt;
#pragma unroll
        for (int n = 0; n < 4; ++n) {
            int col = kta * 64 + n * 16 + (lane & 15);
#pragma unroll
            for (int r = 0; r < 4; ++r) {
                float s = acc[kt][n][r] * 0.0625f;          // * 256^-0.5
                float t = __expf(s * 0.04f);                // e^{2s/50}
                float v = 50.0f * (t - 1.0f) / (t + 1.0f);  // 50*tanh(s/50)
                int rowg = row_g0 + r;
                bool ok = (kta >= 0) && (col <= rowg) && (rowg - col < 512);
                float pv_ = ok ? v : -1e9f;
                acc[kt][n][r] = pv_;
                mx[r] = fmaxf(mx[r], pv_);
            }
        }
    }
#pragma unroll
    for (int o = 1; o < 16; o <<= 1) {
#pragma unroll
        for (int r = 0; r < 4; ++r) mx[r] = fmaxf(mx[r], __shfl_xor(mx[r], o, 64));
    }
    // exp + row sum
    f32x4 sm = {0.f, 0.f, 0.f, 0.f};
#pragma unroll
    for (int kt = 0; kt < 9; ++kt)
#pragma unroll
        for (int n = 0; n < 4; ++n)
#pragma unroll
            for (int r = 0; r < 4; ++r) {
                float e = __expf(acc[kt][n][r] - mx[r]);    // masked -> 0
                acc[kt][n][r] = e;
                sm[r] += e;
            }
#pragma unroll
    for (int o = 1; o < 16; o <<= 1) {
#pragma unroll
        for (int r = 0; r < 4; ++r) sm[r] += __shfl_xor(sm[r], o, 64);
    }
    f32x4 inv;
#pragma unroll
    for (int r = 0; r < 4; ++r) inv[r] = 1.0f / sm[r];

    // write normalized band
#pragma unroll
    for (int kt = 0; kt < 9; ++kt) {
        int kta = qt - 8 + kt;
        if (kta >= 0) {
#pragma unroll
            for (int n = 0; n < 4; ++n) {
                int col = kta * 64 + n * 16 + (lane & 15);
#pragma unroll
                for (int r = 0; r < 4; ++r)
                    probs[((size_t)bh * 2048 + row_g0 + r) * 2048 + col] = acc[kt][n][r] * inv[r];
            }
        }
    }
    // zeros outside band (this wave's 16 rows), float4-vectorized
    int kt0 = qt > 8 ? qt - 8 : 0;
    int pre = kt0 * 64;
    int suf = (qt + 1) * 64;
    float4 z4 = make_float4(0.f, 0.f, 0.f, 0.f);
    for (int r = 0; r < 16; ++r) {
        float* rp = probs + ((size_t)bh * 2048 + qt * 64 + w * 16 + r) * 2048;
        for (int off = lane * 4; off < pre; off += 256) *(float4*)(rp + off) = z4;
        for (int off = suf + lane * 4; off < 2048; off += 256) *(float4*)(rp + off) = z4;
    }
}

// ---------------- PV: attn[b][s][h*256+d] = probs @ V ----------------------
__global__ __launch_bounds__(256) void pv_k(const float* __restrict__ probs, const f16* __restrict__ vt,
                                            f16* __restrict__ attn) {
    int qt = blockIdx.x, bh = blockIdx.y;
    int b = bh >> 3, h = bh & 7;
    __shared__ __align__(16) f16 Vs[256 * 64];   // [d][key]
    int tid = threadIdx.x, lane = tid & 63, wid = tid >> 6;
    int kt0 = qt > 8 ? qt - 8 : 0;
    const f16* vtb = vt + (size_t)((b * 4 + (h >> 1)) * 256) * 2048;
    char* vsb = (char*)Vs;
    f32x4 acc[16] = {};
    const float* prow0 = probs + ((size_t)bh * 2048 + qt * 64 + wid * 16 + (lane & 15)) * 2048 + (lane >> 4) * 8;
    for (int kt = kt0; kt <= qt; ++kt) {
#pragma unroll
        for (int is = 0; is < 8; ++is) {
            int off = is * 4096 + wid * 1024 + lane * 16;
            int d = off >> 7;
            int ke = (off & 127) >> 1;
            gld16(vtb + (size_t)d * 2048 + kt * 64 + ke, vsb + is * 4096 + wid * 1024);
        }
        const float* pr = prow0 + kt * 64;
        float4 xa = *(const float4*)(pr);
        float4 xb = *(const float4*)(pr + 4);
        float4 xc = *(const float4*)(pr + 32);
        float4 xd = *(const float4*)(pr + 36);
        f16x8 a0, a1;
        a0[0] = (f16)xa.x; a0[1] = (f16)xa.y; a0[2] = (f16)xa.z; a0[3] = (f16)xa.w;
        a0[4] = (f16)xb.x; a0[5] = (f16)xb.y; a0[6] = (f16)xb.z; a0[7] = (f16)xb.w;
        a1[0] = (f16)xc.x; a1[1] = (f16)xc.y; a1[2] = (f16)xc.z; a1[3] = (f16)xc.w;
        a1[4] = (f16)xd.x; a1[5] = (f16)xd.y; a1[6] = (f16)xd.z; a1[7] = (f16)xd.w;
        __syncthreads();
#pragma unroll
        for (int n = 0; n < 16; ++n) {
            f16x8 b0 = *(const f16x8*)(vsb + ((n * 16 + (lane & 15)) * 64 + (lane >> 4) * 8) * 2);
            f16x8 b1 = *(const f16x8*)(vsb + ((n * 16 + (lane & 15)) * 64 + 32 + (lane >> 4) * 8) * 2);
            acc[n] = MFMA16(a0, b0, acc[n]);
            acc[n] = MFMA16(a1, b1, acc[n]);
        }
        __syncthreads();
    }
    size_t obase = ((size_t)b * 2048 + qt * 64 + wid * 16 + ((lane >> 4) << 2)) * 2048 + h * 256;
#pragma unroll
    for (int n = 0; n < 16; ++n) {
        int col = n * 16 + (lane & 15);
#pragma unroll
        for (int r = 0; r < 4; ++r)
            attn[obase + (size_t)r * 2048 + col] = (f16)acc[n][r];
    }
}

extern "C" void kernel_launch(void* const* d_in, const int* in_sizes, int n_in,
                              void* d_out, int out_size, void* d_ws, size_t ws_size,
                              hipStream_t stream) {
    (void)in_sizes; (void)n_in; (void)out_size; (void)ws_size;
    const float* hs   = (const float*)d_in[0];
    const float* cosb = (const float*)d_in[1];
    const float* sinb = (const float*)d_in[2];
    const float* qw   = (const float*)d_in[4];
    const float* kw   = (const float*)d_in[5];
    const float* vw   = (const float*)d_in[6];
    const float* ow   = (const float*)d_in[7];
    const float* qnw  = (const float*)d_in[8];
    const float* knw  = (const float*)d_in[9];

    float* out = (float*)d_out;
    float* probs = out + (size_t)2 * 2048 * 2560;          // output 1

    char* ws = (char*)d_ws;
    f16* hsb    = (f16*)(ws);                              // 20,971,520 B
    f16* wqkv   = (f16*)(ws + 20971520);                   // 20,971,520 B
    f16* owb    = (f16*)(ws + 41943040);                   // 10,485,760 B
    float* qkvf = (float*)(ws + 52428800);                 // 67,108,864 B
    f16* qr     = (f16*)(ws + 119537664);                  // 16,777,216 B
    f16* kr     = (f16*)(ws + 136314880);                  //  8,388,608 B
    f16* vt     = (f16*)(ws + 144703488);                  //  8,388,608 B
    f16* attn   = (f16*)(ws + 153092096);                  // 16,777,216 B

    // fp32 -> fp16 casts
    cvt_f32_f16<<<5120, 256, 0, stream>>>(hs, hsb, 10485760);
    cvt_f32_f16<<<2560, 256, 0, stream>>>(qw, wqkv, 5242880);
    cvt_f32_f16<<<1280, 256, 0, stream>>>(kw, wqkv + 5242880, 2621440);
    cvt_f32_f16<<<1280, 256, 0, stream>>>(vw, wqkv + 7864320, 2621440);
    cvt_f32_f16<<<2560, 256, 0, stream>>>(ow, owb, 5242880);

    // fused QKV projection
    gemm_bt<<<dim3(32, 32), 256, 0, stream>>>(hsb, wqkv, qkvf, 4096, 4096, 2560);

    // RMSNorm + RoPE; V cast+transpose (LDS-tiled)
    rmsrope_k<<<12288, 256, 0, stream>>>(qkvf, cosb, sinb, qnw, knw, qr, kr);
    vtrans2<<<256, 256, 0, stream>>>(qkvf, vt);

    // fused scores+softcap+mask+softmax -> probs (full rows, single pass)
    sscore_k<<<dim3(32, 16), 256, 0, stream>>>(qr, kr, probs);

    // PV -> attn [B,S,H*256] f16
    pv_k<<<dim3(32, 16), 256, 0, stream>>>(probs, vt, attn);

    // O projection (output 0)
    gemm_bt<<<dim3(20, 32), 256, 0, stream>>>(attn, owb, out, 4096, 2560, 2048);
}

// Round 4
// 384.582 us; speedup vs baseline: 1.1431x; 1.1275x over previous
//
#include <hip/hip_runtime.h>

typedef _Float16 f16;
typedef float f32x4 __attribute__((ext_vector_type(4)));
typedef _Float16 f16x8 __attribute__((ext_vector_type(8)));
typedef _Float16 f16x4 __attribute__((ext_vector_type(4)));
typedef _Float16 f16x2 __attribute__((ext_vector_type(2)));

#define MFMA16(a, b, c) __builtin_amdgcn_mfma_f32_16x16x32_f16((a), (b), (c), 0, 0, 0)

__device__ __forceinline__ void gld16(const void* g, void* l) {
    __builtin_amdgcn_global_load_lds((const __attribute__((address_space(1))) unsigned int*)g,
                                     (__attribute__((address_space(3))) unsigned int*)l, 16, 0, 0);
}

// ---------------- fp32 -> fp16 cast (8 elems/thread) ----------------
__global__ __launch_bounds__(256) void cvt_f32_f16(const float* __restrict__ src,
                                                   f16* __restrict__ dst, int n) {
    int i = (blockIdx.x * 256 + threadIdx.x) * 8;
    if (i >= n) return;
    float4 a = *(const float4*)(src + i);
    float4 b = *(const float4*)(src + i + 4);
    f16x8 o;
    o[0] = (f16)a.x; o[1] = (f16)a.y; o[2] = (f16)a.z; o[3] = (f16)a.w;
    o[4] = (f16)b.x; o[5] = (f16)b.y; o[6] = (f16)b.z; o[7] = (f16)b.w;
    *(f16x8*)(dst + i) = o;
}

// ============ QKV GEMM: 256x256 tile, BK=32, depth-3 counted-vmcnt pipeline =
// C[4096,4096] = A[4096,2560] * W[4096,2560]^T, f16 in, f32 out.
// 512 threads = 8 waves (2 Mx4 N). LDS: 4 buffers x (A 16K + B 16K) = 128 KiB.
// Swizzle f(o) = o ^ (((o>>6)&3)<<4): involution, 16B-preserving, applied to
// global SOURCE at stage time and to ds_read addr (rule #21 both-sides).
#define QK 2560
#define QN 4096
#define QNT 80

__global__ __launch_bounds__(512, 1) void qkv_gemm(const f16* __restrict__ A, const f16* __restrict__ W,
                                                   float* __restrict__ C) {
    __shared__ __align__(16) char lds[131072];
    const int tid = threadIdx.x;
    const int lane = tid & 63, wid = tid >> 6;
    const int wr = wid >> 2, wc = wid & 3;         // 2x4 wave grid
    int bid = blockIdx.x;                          // 256 blocks
    int swz = (bid & 7) * 32 + (bid >> 3);         // XCD-aware (T1), 256%8==0
    const int m0 = (swz >> 4) * 256, n0 = (swz & 15) * 256;

    // ---- staging source pointers (pre-swizzled k within 32-elem row) ----
    const int kel = 8 * ((tid & 3) ^ ((tid >> 2) & 3));
    const f16* pA0 = A + (size_t)(m0 + (tid >> 2)) * QK + kel;
    const f16* pA1 = pA0 + (size_t)128 * QK;
    const f16* pB0 = W + (size_t)(n0 + (tid >> 2)) * QK + kel;
    const f16* pB1 = pB0 + (size_t)128 * QK;
    const int dst_o = tid * 16;

#define QSTAGE(bi, t)                                                     \
    {                                                                     \
        char* ab_ = lds + (bi) * 32768;                                   \
        int k0_ = (t) * 32;                                               \
        gld16(pA0 + k0_, ab_ + dst_o);                                    \
        gld16(pA1 + k0_, ab_ + 8192 + dst_o);                             \
        gld16(pB0 + k0_, ab_ + 16384 + dst_o);                            \
        gld16(pB1 + k0_, ab_ + 24576 + dst_o);                            \
    }

    // ---- fragment read addresses (swizzled) ----
    const int ccx = (((lane >> 4) << 4) ^ ((lane & 3) << 4));  // swizzled k-byte
    const int ar = wr * 128 + (lane & 15);                     // A row base (+m*16)
    const int br = wc * 64 + (lane & 15);                      // B row base (+n*16)

    f32x4 acc[8][4] = {};

#define QCOMPUTE(bi)                                                      \
    {                                                                     \
        const char* ab_ = lds + (bi) * 32768;                             \
        const char* bb_ = ab_ + 16384;                                    \
        f16x8 Af[8], Bf[4];                                               \
        _Pragma("unroll")                                                 \
        for (int m = 0; m < 8; ++m)                                       \
            Af[m] = *(const f16x8*)(ab_ + (ar + m * 16) * 64 + ccx);      \
        _Pragma("unroll")                                                 \
        for (int n = 0; n < 4; ++n)                                       \
            Bf[n] = *(const f16x8*)(bb_ + (br + n * 16) * 64 + ccx);      \
        __builtin_amdgcn_s_setprio(1);                                    \
        _Pragma("unroll")                                                 \
        for (int m = 0; m < 8; ++m)                                       \
            _Pragma("unroll")                                             \
            for (int n = 0; n < 4; ++n)                                   \
                acc[m][n] = MFMA16(Af[m], Bf[n], acc[m][n]);              \
        __builtin_amdgcn_s_setprio(0);                                    \
    }

    // ---- prologue: stage tiles 0,1,2; wait tile0 ----
    QSTAGE(0, 0)
    QSTAGE(1, 1)
    QSTAGE(2, 2)
    asm volatile("s_waitcnt vmcnt(8)" ::: "memory");
    __builtin_amdgcn_s_barrier();

    // ---- main loop: t = 0..QNT-4, steady-state vmcnt(8) ----
#pragma unroll 1
    for (int t = 0; t < QNT - 3; ++t) {
        QCOMPUTE(t & 3)
        asm volatile("s_waitcnt lgkmcnt(0)" ::: "memory");
        __builtin_amdgcn_s_barrier();                  // all waves done reading buf t
        QSTAGE((t + 3) & 3, t + 3)                     // overwrite buf of tile t-1
        asm volatile("s_waitcnt vmcnt(8)" ::: "memory");  // tile t+1 landed (mine)
        __builtin_amdgcn_s_barrier();                  // -> landed for ALL waves
    }
    // ---- tail: t = QNT-3, QNT-2, QNT-1 ----
    QCOMPUTE((QNT - 3) & 3)
    asm volatile("s_waitcnt lgkmcnt(0)" ::: "memory");
    __builtin_amdgcn_s_barrier();
    asm volatile("s_waitcnt vmcnt(4)" ::: "memory");
    __builtin_amdgcn_s_barrier();
    QCOMPUTE((QNT - 2) & 3)
    asm volatile("s_waitcnt lgkmcnt(0)" ::: "memory");
    __builtin_amdgcn_s_barrier();
    asm volatile("s_waitcnt vmcnt(0)" ::: "memory");
    __builtin_amdgcn_s_barrier();
    QCOMPUTE((QNT - 1) & 3)

    // ---- epilogue: f32 C store ----
#pragma unroll
    for (int m = 0; m < 8; ++m) {
        int row = m0 + wr * 128 + m * 16 + ((lane >> 4) << 2);
#pragma unroll
        for (int n = 0; n < 4; ++n) {
            int col = n0 + wc * 64 + n * 16 + (lane & 15);
#pragma unroll
            for (int r = 0; r < 4; ++r)
                C[(size_t)(row + r) * QN + col] = acc[m][n][r];
        }
    }
#undef QSTAGE
#undef QCOMPUTE
}

// ---------------- GEMM: C[M,N] = A[M,K] * W[N,K]^T  (m97 128^2, O-proj) -----
__global__ __launch_bounds__(256) void gemm_bt(const f16* __restrict__ A, const f16* __restrict__ W,
                                               float* __restrict__ C, int M, int N, int K) {
    __shared__ __align__(16) f16 As[128 * 32];
    __shared__ __align__(16) f16 Bs[128 * 32];
    const int tid = threadIdx.x;
    const int lane = tid & 63, wid = tid >> 6;
    const int wr = wid >> 1, wc = wid & 1;
    const int m0 = blockIdx.y * 128, n0 = blockIdx.x * 128;
    f32x4 acc[4][4] = {};

    const int off0 = wid * 1024 + lane * 16;
    const int off1 = off0 + 4096;
    const int r0 = off0 >> 6, kc0 = (off0 & 63) >> 1;
    const int r1 = off1 >> 6, kc1 = (off1 & 63) >> 1;
    const f16* a0p = A + (size_t)(m0 + r0) * K + kc0;
    const f16* a1p = A + (size_t)(m0 + r1) * K + kc1;
    const f16* b0p = W + (size_t)(n0 + r0) * K + kc0;
    const f16* b1p = W + (size_t)(n0 + r1) * K + kc1;
    char* asb = (char*)As;
    char* bsb = (char*)Bs;

    for (int k0 = 0; k0 < K; k0 += 32) {
        gld16(a0p + k0, asb + wid * 1024);
        gld16(a1p + k0, asb + 4096 + wid * 1024);
        gld16(b0p + k0, bsb + wid * 1024);
        gld16(b1p + k0, bsb + 4096 + wid * 1024);
        __syncthreads();
        f16x8 af[4], bfr[4];
#pragma unroll
        for (int m = 0; m < 4; ++m)
            af[m] = *(const f16x8*)(asb + ((wr * 64 + m * 16 + (lane & 15)) * 32 + (lane >> 4) * 8) * 2);
#pragma unroll
        for (int n = 0; n < 4; ++n)
            bfr[n] = *(const f16x8*)(bsb + ((wc * 64 + n * 16 + (lane & 15)) * 32 + (lane >> 4) * 8) * 2);
#pragma unroll
        for (int m = 0; m < 4; ++m)
#pragma unroll
            for (int n = 0; n < 4; ++n)
                acc[m][n] = MFMA16(af[m], bfr[n], acc[m][n]);
        __syncthreads();
    }
#pragma unroll
    for (int m = 0; m < 4; ++m) {
        int row = m0 + wr * 64 + m * 16 + ((lane >> 4) << 2);
#pragma unroll
        for (int n = 0; n < 4; ++n) {
            int col = n0 + wc * 64 + n * 16 + (lane & 15);
#pragma unroll
            for (int r = 0; r < 4; ++r)
                C[(size_t)(row + r) * N + col] = acc[m][n][r];
        }
    }
}

// ---------------- RMSNorm + RoPE for q and k; one wave per (b,s,head) -------
__global__ __launch_bounds__(256) void rmsrope_k(const float* __restrict__ qkv,
                                                 const float* __restrict__ cosb, const float* __restrict__ sinb,
                                                 const float* __restrict__ qnw, const float* __restrict__ knw,
                                                 f16* __restrict__ qr, f16* __restrict__ kr) {
    int wid = threadIdx.x >> 6, lane = threadIdx.x & 63;
    int task = blockIdx.x * 4 + wid;           // < B*S*12
    int slot = task % 12;
    int bs = task / 12;
    int b = bs >> 11, s = bs & 2047;
    const float* src;
    const float* w;
    f16* dst;
    if (slot < 8) {
        src = qkv + (size_t)bs * 4096 + slot * 256;
        w = qnw;
        dst = qr + ((size_t)(b * 8 + slot) * 2048 + s) * 256;
    } else {
        int h = slot - 8;
        src = qkv + (size_t)bs * 4096 + 2048 + h * 256;
        w = knw;
        dst = kr + ((size_t)(b * 4 + h) * 2048 + s) * 256;
    }
    int i = lane * 4;
    float4 x = *(const float4*)(src + i);
    float ss = x.x * x.x + x.y * x.y + x.z * x.z + x.w * x.w;
#pragma unroll
    for (int o = 32; o; o >>= 1) ss += __shfl_xor(ss, o, 64);
    float rs = rsqrtf(ss * (1.0f / 256.0f) + 1e-6f);
    float4 y;
    y.x = __shfl_xor(x.x, 32, 64);
    y.y = __shfl_xor(x.y, 32, 64);
    y.z = __shfl_xor(x.z, 32, 64);
    y.w = __shfl_xor(x.w, 32, 64);
    float4 wv = *(const float4*)(w + i);
    float4 wp = *(const float4*)(w + (i ^ 128));
    float4 c = *(const float4*)(cosb + (size_t)bs * 256 + i);
    float4 sn = *(const float4*)(sinb + (size_t)bs * 256 + i);
    float sgn = (lane < 32) ? -1.0f : 1.0f;
    float n0 = x.x * rs * (1.f + wv.x), n1 = x.y * rs * (1.f + wv.y);
    float n2 = x.z * rs * (1.f + wv.z), n3 = x.w * rs * (1.f + wv.w);
    float r0 = y.x * rs * (1.f + wp.x) * sgn, r1 = y.y * rs * (1.f + wp.y) * sgn;
    float r2 = y.z * rs * (1.f + wp.z) * sgn, r3 = y.w * rs * (1.f + wp.w) * sgn;
    float o0 = n0 * c.x + r0 * sn.x;
    float o1 = n1 * c.y + r1 * sn.y;
    float o2 = n2 * c.z + r2 * sn.z;
    float o3 = n3 * c.w + r3 * sn.w;
    f16x4 outv;
    outv[0] = (f16)o0; outv[1] = (f16)o1; outv[2] = (f16)o2; outv[3] = (f16)o3;
    *(f16x4*)(dst + i) = outv;
}

// ---------------- V: cast + transpose via LDS -> vt[b][kvh][d][s] (f16) -----
__global__ __launch_bounds__(256) void vtrans2(const float* __restrict__ qkv, f16* __restrict__ vt) {
    __shared__ __align__(16) char Ls[64 * 516];
    int tile = blockIdx.x;           // 0..255
    int st = tile & 31;
    int by = tile >> 5;              // b*4 + kvh
    int b = by >> 2, kvh = by & 3;
    int tid = threadIdx.x;
    int s0 = st * 64;
    const float* src = qkv + ((size_t)(b * 2048 + s0)) * 4096 + 3072 + kvh * 256;
#pragma unroll
    for (int it = 0; it < 16; ++it) {
        int idx = it * 256 + tid;
        int srow = idx >> 6;
        int col = (idx & 63) * 4;
        float4 x = *(const float4*)(src + (size_t)srow * 4096 + col);
        f16x2 lo, hi;
        lo[0] = (f16)x.x; lo[1] = (f16)x.y;
        hi[0] = (f16)x.z; hi[1] = (f16)x.w;
        *(f16x2*)(Ls + srow * 516 + col * 2) = lo;
        *(f16x2*)(Ls + srow * 516 + col * 2 + 4) = hi;
    }
    __syncthreads();
    f16* dst = vt + ((size_t)(by * 256) * 2048) + s0;
#pragma unroll
    for (int p = 0; p < 8; ++p) {
        int d = p * 32 + (tid >> 3);
        int s8 = (tid & 7) * 8;
        f16x8 o;
#pragma unroll
        for (int j = 0; j < 8; ++j)
            o[j] = *(const f16*)(Ls + (s8 + j) * 516 + d * 2);
        *(f16x8*)(dst + (size_t)d * 2048 + s8) = o;
    }
}

// ------------- fused scores + softcap + mask + softmax -> probs -------------
__global__ __launch_bounds__(256) void sscore_k(const f16* __restrict__ qr, const f16* __restrict__ kr,
                                                float* __restrict__ probs) {
    int qt = blockIdx.x, bh = blockIdx.y;
    int b = bh >> 3, h = bh & 7;
    int tid = threadIdx.x, lane = tid & 63, w = tid >> 6;
    __shared__ __align__(16) f16 Ks[64 * 256];
    char* ksb = (char*)Ks;

    const f16* qbase = qr + ((size_t)bh * 2048 + qt * 64 + w * 16 + (lane & 15)) * 256 + (lane >> 4) * 8;
    f16x8 af[8];
#pragma unroll
    for (int ks = 0; ks < 8; ++ks) af[ks] = *(const f16x8*)(qbase + ks * 32);

    f32x4 acc[9][4] = {};
    const f16* kb0 = kr + ((size_t)((b * 4 + (h >> 1)) * 2048)) * 256;
#pragma unroll
    for (int kt = 0; kt < 9; ++kt) {
        int kta = qt - 8 + kt;
        if (kta >= 0) {
            const f16* kbase = kb0 + (size_t)kta * 64 * 256;
#pragma unroll
            for (int is = 0; is < 8; ++is) {
                int off = is * 4096 + w * 1024 + lane * 16;
                int row = off >> 9;
                int ke = (off & 511) >> 1;
                gld16(kbase + (size_t)row * 256 + ke, ksb + is * 4096 + w * 1024);
            }
            __syncthreads();
#pragma unroll
            for (int n = 0; n < 4; ++n)
#pragma unroll
                for (int ks = 0; ks < 8; ++ks) {
                    f16x8 bfr = *(const f16x8*)(ksb + ((n * 16 + (lane & 15)) * 256 + ks * 32 + (lane >> 4) * 8) * 2);
                    acc[kt][n] = MFMA16(af[ks], bfr, acc[kt][n]);
                }
            __syncthreads();
        }
    }

    int row_l = w * 16 + ((lane >> 4) << 2);
    int row_g0 = qt * 64 + row_l;
    f32x4 mx = {-1e30f, -1e30f, -1e30f, -1e30f};
#pragma unroll
    for (int kt = 0; kt < 9; ++kt) {
        int kta = qt - 8 + kt;
#pragma unroll
        for (int n = 0; n < 4; ++n) {
            int col = kta * 64 + n * 16 + (lane & 15);
#pragma unroll
            for (int r = 0; r < 4; ++r) {
                float s = acc[kt][n][r] * 0.0625f;
                float t = __expf(s * 0.04f);
                float v = 50.0f * (t - 1.0f) / (t + 1.0f);
                int rowg = row_g0 + r;
                bool ok = (kta >= 0) && (col <= rowg) && (rowg - col < 512);
                float pv_ = ok ? v : -1e9f;
                acc[kt][n][r] = pv_;
                mx[r] = fmaxf(mx[r], pv_);
            }
        }
    }
#pragma unroll
    for (int o = 1; o < 16; o <<= 1) {
#pragma unroll
        for (int r = 0; r < 4; ++r) mx[r] = fmaxf(mx[r], __shfl_xor(mx[r], o, 64));
    }
    f32x4 sm = {0.f, 0.f, 0.f, 0.f};
#pragma unroll
    for (int kt = 0; kt < 9; ++kt)
#pragma unroll
        for (int n = 0; n < 4; ++n)
#pragma unroll
            for (int r = 0; r < 4; ++r) {
                float e = __expf(acc[kt][n][r] - mx[r]);
                acc[kt][n][r] = e;
                sm[r] += e;
            }
#pragma unroll
    for (int o = 1; o < 16; o <<= 1) {
#pragma unroll
        for (int r = 0; r < 4; ++r) sm[r] += __shfl_xor(sm[r], o, 64);
    }
    f32x4 inv;
#pragma unroll
    for (int r = 0; r < 4; ++r) inv[r] = 1.0f / sm[r];

#pragma unroll
    for (int kt = 0; kt < 9; ++kt) {
        int kta = qt - 8 + kt;
        if (kta >= 0) {
#pragma unroll
            for (int n = 0; n < 4; ++n) {
                int col = kta * 64 + n * 16 + (lane & 15);
#pragma unroll
                for (int r = 0; r < 4; ++r)
                    probs[((size_t)bh * 2048 + row_g0 + r) * 2048 + col] = acc[kt][n][r] * inv[r];
            }
        }
    }
    int kt0 = qt > 8 ? qt - 8 : 0;
    int pre = kt0 * 64;
    int suf = (qt + 1) * 64;
    float4 z4 = make_float4(0.f, 0.f, 0.f, 0.f);
    for (int r = 0; r < 16; ++r) {
        float* rp = probs + ((size_t)bh * 2048 + qt * 64 + w * 16 + r) * 2048;
        for (int off = lane * 4; off < pre; off += 256) *(float4*)(rp + off) = z4;
        for (int off = suf + lane * 4; off < 2048; off += 256) *(float4*)(rp + off) = z4;
    }
}

// ---------------- PV: attn[b][s][h*256+d] = probs @ V ----------------------
__global__ __launch_bounds__(256) void pv_k(const float* __restrict__ probs, const f16* __restrict__ vt,
                                            f16* __restrict__ attn) {
    int qt = blockIdx.x, bh = blockIdx.y;
    int b = bh >> 3, h = bh & 7;
    __shared__ __align__(16) f16 Vs[256 * 64];
    int tid = threadIdx.x, lane = tid & 63, wid = tid >> 6;
    int kt0 = qt > 8 ? qt - 8 : 0;
    const f16* vtb = vt + (size_t)((b * 4 + (h >> 1)) * 256) * 2048;
    char* vsb = (char*)Vs;
    f32x4 acc[16] = {};
    const float* prow0 = probs + ((size_t)bh * 2048 + qt * 64 + wid * 16 + (lane & 15)) * 2048 + (lane >> 4) * 8;
    for (int kt = kt0; kt <= qt; ++kt) {
#pragma unroll
        for (int is = 0; is < 8; ++is) {
            int off = is * 4096 + wid * 1024 + lane * 16;
            int d = off >> 7;
            int ke = (off & 127) >> 1;
            gld16(vtb + (size_t)d * 2048 + kt * 64 + ke, vsb + is * 4096 + wid * 1024);
        }
        const float* pr = prow0 + kt * 64;
        float4 xa = *(const float4*)(pr);
        float4 xb = *(const float4*)(pr + 4);
        float4 xc = *(const float4*)(pr + 32);
        float4 xd = *(const float4*)(pr + 36);
        f16x8 a0, a1;
        a0[0] = (f16)xa.x; a0[1] = (f16)xa.y; a0[2] = (f16)xa.z; a0[3] = (f16)xa.w;
        a0[4] = (f16)xb.x; a0[5] = (f16)xb.y; a0[6] = (f16)xb.z; a0[7] = (f16)xb.w;
        a1[0] = (f16)xc.x; a1[1] = (f16)xc.y; a1[2] = (f16)xc.z; a1[3] = (f16)xc.w;
        a1[4] = (f16)xd.x; a1[5] = (f16)xd.y; a1[6] = (f16)xd.z; a1[7] = (f16)xd.w;
        __syncthreads();
#pragma unroll
        for (int n = 0; n < 16; ++n) {
            f16x8 b0 = *(const f16x8*)(vsb + ((n * 16 + (lane & 15)) * 64 + (lane >> 4) * 8) * 2);
            f16x8 b1 = *(const f16x8*)(vsb + ((n * 16 + (lane & 15)) * 64 + 32 + (lane >> 4) * 8) * 2);
            acc[n] = MFMA16(a0, b0, acc[n]);
            acc[n] = MFMA16(a1, b1, acc[n]);
        }
        __syncthreads();
    }
    size_t obase = ((size_t)b * 2048 + qt * 64 + wid * 16 + ((lane >> 4) << 2)) * 2048 + h * 256;
#pragma unroll
    for (int n = 0; n < 16; ++n) {
        int col = n * 16 + (lane & 15);
#pragma unroll
        for (int r = 0; r < 4; ++r)
            attn[obase + (size_t)r * 2048 + col] = (f16)acc[n][r];
    }
}

extern "C" void kernel_launch(void* const* d_in, const int* in_sizes, int n_in,
                              void* d_out, int out_size, void* d_ws, size_t ws_size,
                              hipStream_t stream) {
    (void)in_sizes; (void)n_in; (void)out_size; (void)ws_size;
    const float* hs   = (const float*)d_in[0];
    const float* cosb = (const float*)d_in[1];
    const float* sinb = (const float*)d_in[2];
    const float* qw   = (const float*)d_in[4];
    const float* kw   = (const float*)d_in[5];
    const float* vw   = (const float*)d_in[6];
    const float* ow   = (const float*)d_in[7];
    const float* qnw  = (const float*)d_in[8];
    const float* knw  = (const float*)d_in[9];

    float* out = (float*)d_out;
    float* probs = out + (size_t)2 * 2048 * 2560;          // output 1

    char* ws = (char*)d_ws;
    f16* hsb    = (f16*)(ws);                              // 20,971,520 B
    f16* wqkv   = (f16*)(ws + 20971520);                   // 20,971,520 B
    f16* owb    = (f16*)(ws + 41943040);                   // 10,485,760 B
    float* qkvf = (float*)(ws + 52428800);                 // 67,108,864 B
    f16* qr     = (f16*)(ws + 119537664);                  // 16,777,216 B
    f16* kr     = (f16*)(ws + 136314880);                  //  8,388,608 B
    f16* vt     = (f16*)(ws + 144703488);                  //  8,388,608 B
    f16* attn   = (f16*)(ws + 153092096);                  // 16,777,216 B

    // fp32 -> fp16 casts
    cvt_f32_f16<<<5120, 256, 0, stream>>>(hs, hsb, 10485760);
    cvt_f32_f16<<<2560, 256, 0, stream>>>(qw, wqkv, 5242880);
    cvt_f32_f16<<<1280, 256, 0, stream>>>(kw, wqkv + 5242880, 2621440);
    cvt_f32_f16<<<1280, 256, 0, stream>>>(vw, wqkv + 7864320, 2621440);
    cvt_f32_f16<<<2560, 256, 0, stream>>>(ow, owb, 5242880);

    // fused QKV projection: 256^2 deep-pipelined (T1+T2+T4+T5)
    qkv_gemm<<<256, 512, 0, stream>>>(hsb, wqkv, qkvf);

    // RMSNorm + RoPE; V cast+transpose (LDS-tiled)
    rmsrope_k<<<12288, 256, 0, stream>>>(qkvf, cosb, sinb, qnw, knw, qr, kr);
    vtrans2<<<256, 256, 0, stream>>>(qkvf, vt);

    // fused scores+softcap+mask+softmax -> probs (full rows, single pass)
    sscore_k<<<dim3(32, 16), 256, 0, stream>>>(qr, kr, probs);

    // PV -> attn [B,S,H*256] f16
    pv_k<<<dim3(32, 16), 256, 0, stream>>>(probs, vt, attn);

    // O projection (output 0)
    gemm_bt<<<dim3(20, 32), 256, 0, stream>>>(attn, owb, out, 4096, 2560, 2048);
}

// Round 5
// 363.963 us; speedup vs baseline: 1.2079x; 1.0567x over previous
//
#include <hip/hip_runtime.h>

typedef _Float16 f16;
typedef float f32x4 __attribute__((ext_vector_type(4)));
typedef _Float16 f16x8 __attribute__((ext_vector_type(8)));
typedef _Float16 f16x4 __attribute__((ext_vector_type(4)));
typedef _Float16 f16x2 __attribute__((ext_vector_type(2)));

#define MFMA16(a, b, c) __builtin_amdgcn_mfma_f32_16x16x32_f16((a), (b), (c), 0, 0, 0)

__device__ __forceinline__ void gld16(const void* g, void* l) {
    __builtin_amdgcn_global_load_lds((const __attribute__((address_space(1))) unsigned int*)g,
                                     (__attribute__((address_space(3))) unsigned int*)l, 16, 0, 0);
}

// ---------------- merged fp32 -> fp16 cast for all 5 tensors ----------------
// segments (elems): hs 10485760 | qw 5242880 | kw 2621440 | vw 2621440 | ow 5242880
__global__ __launch_bounds__(256) void cvt_all(const float* __restrict__ hs, const float* __restrict__ qw,
                                               const float* __restrict__ kw, const float* __restrict__ vw,
                                               const float* __restrict__ ow, f16* __restrict__ hsb,
                                               f16* __restrict__ wqkv, f16* __restrict__ owb) {
    long g = (long)(blockIdx.x * 256 + threadIdx.x) * 8;
    const float* src;
    f16* dst;
    long off;
    if (g < 10485760L) { src = hs; dst = hsb; off = g; }
    else if (g < 15728640L) { src = qw; dst = wqkv; off = g - 10485760L; }
    else if (g < 18350080L) { src = kw; dst = wqkv + 5242880; off = g - 15728640L; }
    else if (g < 20971520L) { src = vw; dst = wqkv + 7864320; off = g - 18350080L; }
    else { src = ow; dst = owb; off = g - 20971520L; }
    float4 a = *(const float4*)(src + off);
    float4 b = *(const float4*)(src + off + 4);
    f16x8 o;
    o[0] = (f16)a.x; o[1] = (f16)a.y; o[2] = (f16)a.z; o[3] = (f16)a.w;
    o[4] = (f16)b.x; o[5] = (f16)b.y; o[6] = (f16)b.z; o[7] = (f16)b.w;
    *(f16x8*)(dst + off) = o;
}

// ============ 256x256-tile deep-pipelined GEMM (T1+T2+T4+T5) ================
// C[4096,N] = A[4096,K] * W[N,K]^T, f16 in, f16 or f32 out.
// 512 threads = 8 waves (2M x 4N). LDS: 4 bufs x (A 16K + B 16K) = 128 KiB.
// Depth-3 stage-ahead, steady-state s_waitcnt vmcnt(8) (never 0 in loop).
// Swizzle f(o) = o ^ (((o>>6)&3)<<4): involution, 16B-preserving; applied to
// global SOURCE at stage and to ds_read addr (rule #21 both-sides).
template <int K, int N, int GN, bool F16OUT>
__global__ __launch_bounds__(512, 1) void gemm256(const f16* __restrict__ A, const f16* __restrict__ W,
                                                  void* __restrict__ Cv) {
    constexpr int NT = K / 32;
    __shared__ __align__(16) char lds[131072];
    const int tid = threadIdx.x;
    const int lane = tid & 63, wid = tid >> 6;
    const int wr = wid >> 2, wc = wid & 3;
    int bid = blockIdx.x;                              // 16*GN blocks, %8==0
    int swz = (bid & 7) * ((16 * GN) >> 3) + (bid >> 3);
    const int m0 = (swz / GN) * 256, n0 = (swz % GN) * 256;

    const int kel = 8 * ((tid & 3) ^ ((tid >> 2) & 3));   // pre-swizzled k
    const f16* pA0 = A + (size_t)(m0 + (tid >> 2)) * K + kel;
    const f16* pA1 = pA0 + (size_t)128 * K;
    const f16* pB0 = W + (size_t)(n0 + (tid >> 2)) * K + kel;
    const f16* pB1 = pB0 + (size_t)128 * K;
    const int dst_o = tid * 16;

#define QSTAGE(bi, t)                                                     \
    {                                                                     \
        char* ab_ = lds + (bi) * 32768;                                   \
        int k0_ = (t) * 32;                                               \
        gld16(pA0 + k0_, ab_ + dst_o);                                    \
        gld16(pA1 + k0_, ab_ + 8192 + dst_o);                             \
        gld16(pB0 + k0_, ab_ + 16384 + dst_o);                            \
        gld16(pB1 + k0_, ab_ + 24576 + dst_o);                            \
    }

    const int ccx = (((lane >> 4) << 4) ^ ((lane & 3) << 4));
    const int ar = wr * 128 + (lane & 15);
    const int br = wc * 64 + (lane & 15);

    f32x4 acc[8][4] = {};

#define QCOMPUTE(bi)                                                      \
    {                                                                     \
        const char* ab_ = lds + (bi) * 32768;                             \
        const char* bb_ = ab_ + 16384;                                    \
        f16x8 Af[8], Bf[4];                                               \
        _Pragma("unroll")                                                 \
        for (int m = 0; m < 8; ++m)                                       \
            Af[m] = *(const f16x8*)(ab_ + (ar + m * 16) * 64 + ccx);      \
        _Pragma("unroll")                                                 \
        for (int n = 0; n < 4; ++n)                                       \
            Bf[n] = *(const f16x8*)(bb_ + (br + n * 16) * 64 + ccx);      \
        __builtin_amdgcn_s_setprio(1);                                    \
        _Pragma("unroll")                                                 \
        for (int m = 0; m < 8; ++m)                                       \
            _Pragma("unroll")                                             \
            for (int n = 0; n < 4; ++n)                                   \
                acc[m][n] = MFMA16(Af[m], Bf[n], acc[m][n]);              \
        __builtin_amdgcn_s_setprio(0);                                    \
    }

    QSTAGE(0, 0)
    QSTAGE(1, 1)
    QSTAGE(2, 2)
    asm volatile("s_waitcnt vmcnt(8)" ::: "memory");
    __builtin_amdgcn_s_barrier();

#pragma unroll 1
    for (int t = 0; t < NT - 3; ++t) {
        QCOMPUTE(t & 3)
        asm volatile("s_waitcnt lgkmcnt(0)" ::: "memory");
        __builtin_amdgcn_s_barrier();
        QSTAGE((t + 3) & 3, t + 3)
        asm volatile("s_waitcnt vmcnt(8)" ::: "memory");
        __builtin_amdgcn_s_barrier();
    }
    QCOMPUTE((NT - 3) & 3)
    asm volatile("s_waitcnt lgkmcnt(0)" ::: "memory");
    __builtin_amdgcn_s_barrier();
    asm volatile("s_waitcnt vmcnt(4)" ::: "memory");
    __builtin_amdgcn_s_barrier();
    QCOMPUTE((NT - 2) & 3)
    asm volatile("s_waitcnt lgkmcnt(0)" ::: "memory");
    __builtin_amdgcn_s_barrier();
    asm volatile("s_waitcnt vmcnt(0)" ::: "memory");
    __builtin_amdgcn_s_barrier();
    QCOMPUTE((NT - 1) & 3)

#pragma unroll
    for (int m = 0; m < 8; ++m) {
        int row = m0 + wr * 128 + m * 16 + ((lane >> 4) << 2);
#pragma unroll
        for (int n = 0; n < 4; ++n) {
            int col = n0 + wc * 64 + n * 16 + (lane & 15);
#pragma unroll
            for (int r = 0; r < 4; ++r) {
                if constexpr (F16OUT)
                    ((f16*)Cv)[(size_t)(row + r) * N + col] = (f16)acc[m][n][r];
                else
                    ((float*)Cv)[(size_t)(row + r) * N + col] = acc[m][n][r];
            }
        }
    }
#undef QSTAGE
#undef QCOMPUTE
}

// ---------------- RMSNorm + RoPE for q and k; one wave per (b,s,head) -------
// qkvh (f16) layout: [B*S][4096] = [q(8*256) | k(4*256) | v(4*256)]
__global__ __launch_bounds__(256) void rmsrope_k(const f16* __restrict__ qkvh,
                                                 const float* __restrict__ cosb, const float* __restrict__ sinb,
                                                 const float* __restrict__ qnw, const float* __restrict__ knw,
                                                 f16* __restrict__ qr, f16* __restrict__ kr) {
    int wid = threadIdx.x >> 6, lane = threadIdx.x & 63;
    int task = blockIdx.x * 4 + wid;           // < B*S*12
    int slot = task % 12;
    int bs = task / 12;
    int b = bs >> 11, s = bs & 2047;
    const f16* src;
    const float* w;
    f16* dst;
    if (slot < 8) {
        src = qkvh + (size_t)bs * 4096 + slot * 256;
        w = qnw;
        dst = qr + ((size_t)(b * 8 + slot) * 2048 + s) * 256;
    } else {
        int h = slot - 8;
        src = qkvh + (size_t)bs * 4096 + 2048 + h * 256;
        w = knw;
        dst = kr + ((size_t)(b * 4 + h) * 2048 + s) * 256;
    }
    int i = lane * 4;
    f16x4 xr = *(const f16x4*)(src + i);
    float4 x;
    x.x = (float)xr[0]; x.y = (float)xr[1]; x.z = (float)xr[2]; x.w = (float)xr[3];
    float ss = x.x * x.x + x.y * x.y + x.z * x.z + x.w * x.w;
#pragma unroll
    for (int o = 32; o; o >>= 1) ss += __shfl_xor(ss, o, 64);
    float rs = rsqrtf(ss * (1.0f / 256.0f) + 1e-6f);
    float4 y;
    y.x = __shfl_xor(x.x, 32, 64);
    y.y = __shfl_xor(x.y, 32, 64);
    y.z = __shfl_xor(x.z, 32, 64);
    y.w = __shfl_xor(x.w, 32, 64);
    float4 wv = *(const float4*)(w + i);
    float4 wp = *(const float4*)(w + (i ^ 128));
    float4 c = *(const float4*)(cosb + (size_t)bs * 256 + i);
    float4 sn = *(const float4*)(sinb + (size_t)bs * 256 + i);
    float sgn = (lane < 32) ? -1.0f : 1.0f;
    float n0 = x.x * rs * (1.f + wv.x), n1 = x.y * rs * (1.f + wv.y);
    float n2 = x.z * rs * (1.f + wv.z), n3 = x.w * rs * (1.f + wv.w);
    float r0 = y.x * rs * (1.f + wp.x) * sgn, r1 = y.y * rs * (1.f + wp.y) * sgn;
    float r2 = y.z * rs * (1.f + wp.z) * sgn, r3 = y.w * rs * (1.f + wp.w) * sgn;
    float o0 = n0 * c.x + r0 * sn.x;
    float o1 = n1 * c.y + r1 * sn.y;
    float o2 = n2 * c.z + r2 * sn.z;
    float o3 = n3 * c.w + r3 * sn.w;
    f16x4 outv;
    outv[0] = (f16)o0; outv[1] = (f16)o1; outv[2] = (f16)o2; outv[3] = (f16)o3;
    *(f16x4*)(dst + i) = outv;
}

// ---------------- V: transpose via LDS -> vt[b][kvh][d][s] (f16) ------------
// Tile: 64 s x 256 d. Coalesced f16x8 reads, padded LDS (516B rows, 4B writes).
__global__ __launch_bounds__(256) void vtrans2(const f16* __restrict__ qkvh, f16* __restrict__ vt) {
    __shared__ __align__(16) char Ls[64 * 516];
    int tile = blockIdx.x;           // 0..255
    int st = tile & 31;
    int by = tile >> 5;              // b*4 + kvh
    int b = by >> 2, kvh = by & 3;
    int tid = threadIdx.x;
    int s0 = st * 64;
    const f16* src = qkvh + ((size_t)(b * 2048 + s0)) * 4096 + 3072 + kvh * 256;
#pragma unroll
    for (int it = 0; it < 8; ++it) {
        int idx = it * 256 + tid;            // 2048 groups of 8
        int srow = idx >> 5;
        int col8 = (idx & 31) * 8;
        f16x8 x = *(const f16x8*)(src + (size_t)srow * 4096 + col8);
        char* lp = Ls + srow * 516 + col8 * 2;
        *(f16x2*)(lp)      = f16x2{x[0], x[1]};
        *(f16x2*)(lp + 4)  = f16x2{x[2], x[3]};
        *(f16x2*)(lp + 8)  = f16x2{x[4], x[5]};
        *(f16x2*)(lp + 12) = f16x2{x[6], x[7]};
    }
    __syncthreads();
    f16* dst = vt + ((size_t)(by * 256) * 2048) + s0;
#pragma unroll
    for (int p = 0; p < 8; ++p) {
        int d = p * 32 + (tid >> 3);
        int s8 = (tid & 7) * 8;
        f16x8 o;
#pragma unroll
        for (int j = 0; j < 8; ++j)
            o[j] = *(const f16*)(Ls + (s8 + j) * 516 + d * 2);
        *(f16x8*)(dst + (size_t)d * 2048 + s8) = o;
    }
}

// ------------- fused scores + softcap + mask + softmax -> probs -------------
__global__ __launch_bounds__(256) void sscore_k(const f16* __restrict__ qr, const f16* __restrict__ kr,
                                                float* __restrict__ probs) {
    int qt = blockIdx.x, bh = blockIdx.y;
    int b = bh >> 3, h = bh & 7;
    int tid = threadIdx.x, lane = tid & 63, w = tid >> 6;
    __shared__ __align__(16) f16 Ks[64 * 256];
    char* ksb = (char*)Ks;

    const f16* qbase = qr + ((size_t)bh * 2048 + qt * 64 + w * 16 + (lane & 15)) * 256 + (lane >> 4) * 8;
    f16x8 af[8];
#pragma unroll
    for (int ks = 0; ks < 8; ++ks) af[ks] = *(const f16x8*)(qbase + ks * 32);

    f32x4 acc[9][4] = {};
    const f16* kb0 = kr + ((size_t)((b * 4 + (h >> 1)) * 2048)) * 256;
#pragma unroll
    for (int kt = 0; kt < 9; ++kt) {
        int kta = qt - 8 + kt;
        if (kta >= 0) {
            const f16* kbase = kb0 + (size_t)kta * 64 * 256;
#pragma unroll
            for (int is = 0; is < 8; ++is) {
                int off = is * 4096 + w * 1024 + lane * 16;
                int row = off >> 9;
                int ke = (off & 511) >> 1;
                gld16(kbase + (size_t)row * 256 + ke, ksb + is * 4096 + w * 1024);
            }
            __syncthreads();
#pragma unroll
            for (int n = 0; n < 4; ++n)
#pragma unroll
                for (int ks = 0; ks < 8; ++ks) {
                    f16x8 bfr = *(const f16x8*)(ksb + ((n * 16 + (lane & 15)) * 256 + ks * 32 + (lane >> 4) * 8) * 2);
                    acc[kt][n] = MFMA16(af[ks], bfr, acc[kt][n]);
                }
            __syncthreads();
        }
    }

    int row_l = w * 16 + ((lane >> 4) << 2);
    int row_g0 = qt * 64 + row_l;
    f32x4 mx = {-1e30f, -1e30f, -1e30f, -1e30f};
#pragma unroll
    for (int kt = 0; kt < 9; ++kt) {
        int kta = qt - 8 + kt;
#pragma unroll
        for (int n = 0; n < 4; ++n) {
            int col = kta * 64 + n * 16 + (lane & 15);
#pragma unroll
            for (int r = 0; r < 4; ++r) {
                float s = acc[kt][n][r] * 0.0625f;
                float t = __expf(s * 0.04f);
                float v = 50.0f * (t - 1.0f) / (t + 1.0f);
                int rowg = row_g0 + r;
                bool ok = (kta >= 0) && (col <= rowg) && (rowg - col < 512);
                float pv_ = ok ? v : -1e9f;
                acc[kt][n][r] = pv_;
                mx[r] = fmaxf(mx[r], pv_);
            }
        }
    }
#pragma unroll
    for (int o = 1; o < 16; o <<= 1) {
#pragma unroll
        for (int r = 0; r < 4; ++r) mx[r] = fmaxf(mx[r], __shfl_xor(mx[r], o, 64));
    }
    f32x4 sm = {0.f, 0.f, 0.f, 0.f};
#pragma unroll
    for (int kt = 0; kt < 9; ++kt)
#pragma unroll
        for (int n = 0; n < 4; ++n)
#pragma unroll
            for (int r = 0; r < 4; ++r) {
                float e = __expf(acc[kt][n][r] - mx[r]);
                acc[kt][n][r] = e;
                sm[r] += e;
            }
#pragma unroll
    for (int o = 1; o < 16; o <<= 1) {
#pragma unroll
        for (int r = 0; r < 4; ++r) sm[r] += __shfl_xor(sm[r], o, 64);
    }
    f32x4 inv;
#pragma unroll
    for (int r = 0; r < 4; ++r) inv[r] = 1.0f / sm[r];

#pragma unroll
    for (int kt = 0; kt < 9; ++kt) {
        int kta = qt - 8 + kt;
        if (kta >= 0) {
#pragma unroll
            for (int n = 0; n < 4; ++n) {
                int col = kta * 64 + n * 16 + (lane & 15);
#pragma unroll
                for (int r = 0; r < 4; ++r)
                    probs[((size_t)bh * 2048 + row_g0 + r) * 2048 + col] = acc[kt][n][r] * inv[r];
            }
        }
    }
    int kt0 = qt > 8 ? qt - 8 : 0;
    int pre = kt0 * 64;
    int suf = (qt + 1) * 64;
    float4 z4 = make_float4(0.f, 0.f, 0.f, 0.f);
    for (int r = 0; r < 16; ++r) {
        float* rp = probs + ((size_t)bh * 2048 + qt * 64 + w * 16 + r) * 2048;
        for (int off = lane * 4; off < pre; off += 256) *(float4*)(rp + off) = z4;
        for (int off = suf + lane * 4; off < 2048; off += 256) *(float4*)(rp + off) = z4;
    }
}

// ---------------- PV: attn[b][s][h*256+d] = probs @ V ----------------------
__global__ __launch_bounds__(256) void pv_k(const float* __restrict__ probs, const f16* __restrict__ vt,
                                            f16* __restrict__ attn) {
    int qt = blockIdx.x, bh = blockIdx.y;
    int b = bh >> 3, h = bh & 7;
    __shared__ __align__(16) f16 Vs[256 * 64];
    int tid = threadIdx.x, lane = tid & 63, wid = tid >> 6;
    int kt0 = qt > 8 ? qt - 8 : 0;
    const f16* vtb = vt + (size_t)((b * 4 + (h >> 1)) * 256) * 2048;
    char* vsb = (char*)Vs;
    f32x4 acc[16] = {};
    const float* prow0 = probs + ((size_t)bh * 2048 + qt * 64 + wid * 16 + (lane & 15)) * 2048 + (lane >> 4) * 8;
    for (int kt = kt0; kt <= qt; ++kt) {
#pragma unroll
        for (int is = 0; is < 8; ++is) {
            int off = is * 4096 + wid * 1024 + lane * 16;
            int d = off >> 7;
            int ke = (off & 127) >> 1;
            gld16(vtb + (size_t)d * 2048 + kt * 64 + ke, vsb + is * 4096 + wid * 1024);
        }
        const float* pr = prow0 + kt * 64;
        float4 xa = *(const float4*)(pr);
        float4 xb = *(const float4*)(pr + 4);
        float4 xc = *(const float4*)(pr + 32);
        float4 xd = *(const float4*)(pr + 36);
        f16x8 a0, a1;
        a0[0] = (f16)xa.x; a0[1] = (f16)xa.y; a0[2] = (f16)xa.z; a0[3] = (f16)xa.w;
        a0[4] = (f16)xb.x; a0[5] = (f16)xb.y; a0[6] = (f16)xb.z; a0[7] = (f16)xb.w;
        a1[0] = (f16)xc.x; a1[1] = (f16)xc.y; a1[2] = (f16)xc.z; a1[3] = (f16)xc.w;
        a1[4] = (f16)xd.x; a1[5] = (f16)xd.y; a1[6] = (f16)xd.z; a1[7] = (f16)xd.w;
        __syncthreads();
#pragma unroll
        for (int n = 0; n < 16; ++n) {
            f16x8 b0 = *(const f16x8*)(vsb + ((n * 16 + (lane & 15)) * 64 + (lane >> 4) * 8) * 2);
            f16x8 b1 = *(const f16x8*)(vsb + ((n * 16 + (lane & 15)) * 64 + 32 + (lane >> 4) * 8) * 2);
            acc[n] = MFMA16(a0, b0, acc[n]);
            acc[n] = MFMA16(a1, b1, acc[n]);
        }
        __syncthreads();
    }
    size_t obase = ((size_t)b * 2048 + qt * 64 + wid * 16 + ((lane >> 4) << 2)) * 2048 + h * 256;
#pragma unroll
    for (int n = 0; n < 16; ++n) {
        int col = n * 16 + (lane & 15);
#pragma unroll
        for (int r = 0; r < 4; ++r)
            attn[obase + (size_t)r * 2048 + col] = (f16)acc[n][r];
    }
}

extern "C" void kernel_launch(void* const* d_in, const int* in_sizes, int n_in,
                              void* d_out, int out_size, void* d_ws, size_t ws_size,
                              hipStream_t stream) {
    (void)in_sizes; (void)n_in; (void)out_size; (void)ws_size;
    const float* hs   = (const float*)d_in[0];
    const float* cosb = (const float*)d_in[1];
    const float* sinb = (const float*)d_in[2];
    const float* qw   = (const float*)d_in[4];
    const float* kw   = (const float*)d_in[5];
    const float* vw   = (const float*)d_in[6];
    const float* ow   = (const float*)d_in[7];
    const float* qnw  = (const float*)d_in[8];
    const float* knw  = (const float*)d_in[9];

    float* out = (float*)d_out;
    float* probs = out + (size_t)2 * 2048 * 2560;          // output 1

    char* ws = (char*)d_ws;
    f16* hsb  = (f16*)(ws);                                // 20,971,520 B
    f16* wqkv = (f16*)(ws + 20971520);                     // 20,971,520 B
    f16* owb  = (f16*)(ws + 41943040);                     // 10,485,760 B
    f16* qkvh = (f16*)(ws + 52428800);                     // 33,554,432 B (f16 now)
    f16* qr   = (f16*)(ws + 85983232);                     // 16,777,216 B
    f16* kr   = (f16*)(ws + 102760448);                    //  8,388,608 B
    f16* vt   = (f16*)(ws + 111149056);                    //  8,388,608 B
    f16* attn = (f16*)(ws + 119537664);                    // 16,777,216 B -> total 136,314,880 B

    // all fp32 -> fp16 casts in one launch
    cvt_all<<<12800, 256, 0, stream>>>(hs, qw, kw, vw, ow, hsb, wqkv, owb);

    // fused QKV projection: 256^2 deep-pipelined, f16 out
    gemm256<2560, 4096, 16, true><<<256, 512, 0, stream>>>(hsb, wqkv, qkvh);

    // RMSNorm + RoPE; V transpose (LDS-tiled)
    rmsrope_k<<<12288, 256, 0, stream>>>(qkvh, cosb, sinb, qnw, knw, qr, kr);
    vtrans2<<<256, 256, 0, stream>>>(qkvh, vt);

    // fused scores+softcap+mask+softmax -> probs (full rows, single pass)
    sscore_k<<<dim3(32, 16), 256, 0, stream>>>(qr, kr, probs);

    // PV -> attn [B,S,H*256] f16
    pv_k<<<dim3(32, 16), 256, 0, stream>>>(probs, vt, attn);

    // O projection: 256^2 deep-pipelined, f32 out (output 0)
    gemm256<2048, 2560, 10, false><<<160, 512, 0, stream>>>(attn, owb, out);
}

// Round 6
// 356.091 us; speedup vs baseline: 1.2346x; 1.0221x over previous
//
#include <hip/hip_runtime.h>

typedef _Float16 f16;
typedef float f32x4 __attribute__((ext_vector_type(4)));
typedef _Float16 f16x8 __attribute__((ext_vector_type(8)));
typedef _Float16 f16x4 __attribute__((ext_vector_type(4)));
typedef _Float16 f16x2 __attribute__((ext_vector_type(2)));

#define MFMA16(a, b, c) __builtin_amdgcn_mfma_f32_16x16x32_f16((a), (b), (c), 0, 0, 0)

__device__ __forceinline__ void gld16(const void* g, void* l) {
    __builtin_amdgcn_global_load_lds((const __attribute__((address_space(1))) unsigned int*)g,
                                     (__attribute__((address_space(3))) unsigned int*)l, 16, 0, 0);
}

// ---------------- merged fp32 -> fp16 cast for all 5 tensors ----------------
__global__ __launch_bounds__(256) void cvt_all(const float* __restrict__ hs, const float* __restrict__ qw,
                                               const float* __restrict__ kw, const float* __restrict__ vw,
                                               const float* __restrict__ ow, f16* __restrict__ hsb,
                                               f16* __restrict__ wqkv, f16* __restrict__ owb) {
    long g = (long)(blockIdx.x * 256 + threadIdx.x) * 8;
    const float* src;
    f16* dst;
    long off;
    if (g < 10485760L) { src = hs; dst = hsb; off = g; }
    else if (g < 15728640L) { src = qw; dst = wqkv; off = g - 10485760L; }
    else if (g < 18350080L) { src = kw; dst = wqkv + 5242880; off = g - 15728640L; }
    else if (g < 20971520L) { src = vw; dst = wqkv + 7864320; off = g - 18350080L; }
    else { src = ow; dst = owb; off = g - 20971520L; }
    float4 a = *(const float4*)(src + off);
    float4 b = *(const float4*)(src + off + 4);
    f16x8 o;
    o[0] = (f16)a.x; o[1] = (f16)a.y; o[2] = (f16)a.z; o[3] = (f16)a.w;
    o[4] = (f16)b.x; o[5] = (f16)b.y; o[6] = (f16)b.z; o[7] = (f16)b.w;
    *(f16x8*)(dst + off) = o;
}

// ============ 256x256-tile deep-pipelined GEMM (T1+T2+T4+T5) ================
template <int K, int N, int GN, bool F16OUT>
__global__ __launch_bounds__(512, 1) void gemm256(const f16* __restrict__ A, const f16* __restrict__ W,
                                                  void* __restrict__ Cv) {
    constexpr int NT = K / 32;
    __shared__ __align__(16) char lds[131072];
    const int tid = threadIdx.x;
    const int lane = tid & 63, wid = tid >> 6;
    const int wr = wid >> 2, wc = wid & 3;
    int bid = blockIdx.x;
    int swz = (bid & 7) * ((16 * GN) >> 3) + (bid >> 3);
    const int m0 = (swz / GN) * 256, n0 = (swz % GN) * 256;

    const int kel = 8 * ((tid & 3) ^ ((tid >> 2) & 3));
    const f16* pA0 = A + (size_t)(m0 + (tid >> 2)) * K + kel;
    const f16* pA1 = pA0 + (size_t)128 * K;
    const f16* pB0 = W + (size_t)(n0 + (tid >> 2)) * K + kel;
    const f16* pB1 = pB0 + (size_t)128 * K;
    const int dst_o = tid * 16;

#define QSTAGE(bi, t)                                                     \
    {                                                                     \
        char* ab_ = lds + (bi) * 32768;                                   \
        int k0_ = (t) * 32;                                               \
        gld16(pA0 + k0_, ab_ + dst_o);                                    \
        gld16(pA1 + k0_, ab_ + 8192 + dst_o);                             \
        gld16(pB0 + k0_, ab_ + 16384 + dst_o);                            \
        gld16(pB1 + k0_, ab_ + 24576 + dst_o);                            \
    }

    const int ccx = (((lane >> 4) << 4) ^ ((lane & 3) << 4));
    const int ar = wr * 128 + (lane & 15);
    const int br = wc * 64 + (lane & 15);

    f32x4 acc[8][4] = {};

#define QCOMPUTE(bi)                                                      \
    {                                                                     \
        const char* ab_ = lds + (bi) * 32768;                             \
        const char* bb_ = ab_ + 16384;                                    \
        f16x8 Af[8], Bf[4];                                               \
        _Pragma("unroll")                                                 \
        for (int m = 0; m < 8; ++m)                                       \
            Af[m] = *(const f16x8*)(ab_ + (ar + m * 16) * 64 + ccx);      \
        _Pragma("unroll")                                                 \
        for (int n = 0; n < 4; ++n)                                       \
            Bf[n] = *(const f16x8*)(bb_ + (br + n * 16) * 64 + ccx);      \
        __builtin_amdgcn_s_setprio(1);                                    \
        _Pragma("unroll")                                                 \
        for (int m = 0; m < 8; ++m)                                       \
            _Pragma("unroll")                                             \
            for (int n = 0; n < 4; ++n)                                   \
                acc[m][n] = MFMA16(Af[m], Bf[n], acc[m][n]);              \
        __builtin_amdgcn_s_setprio(0);                                    \
    }

    QSTAGE(0, 0)
    QSTAGE(1, 1)
    QSTAGE(2, 2)
    asm volatile("s_waitcnt vmcnt(8)" ::: "memory");
    __builtin_amdgcn_s_barrier();

#pragma unroll 1
    for (int t = 0; t < NT - 3; ++t) {
        QCOMPUTE(t & 3)
        asm volatile("s_waitcnt lgkmcnt(0)" ::: "memory");
        __builtin_amdgcn_s_barrier();
        QSTAGE((t + 3) & 3, t + 3)
        asm volatile("s_waitcnt vmcnt(8)" ::: "memory");
        __builtin_amdgcn_s_barrier();
    }
    QCOMPUTE((NT - 3) & 3)
    asm volatile("s_waitcnt lgkmcnt(0)" ::: "memory");
    __builtin_amdgcn_s_barrier();
    asm volatile("s_waitcnt vmcnt(4)" ::: "memory");
    __builtin_amdgcn_s_barrier();
    QCOMPUTE((NT - 2) & 3)
    asm volatile("s_waitcnt lgkmcnt(0)" ::: "memory");
    __builtin_amdgcn_s_barrier();
    asm volatile("s_waitcnt vmcnt(0)" ::: "memory");
    __builtin_amdgcn_s_barrier();
    QCOMPUTE((NT - 1) & 3)

#pragma unroll
    for (int m = 0; m < 8; ++m) {
        int row = m0 + wr * 128 + m * 16 + ((lane >> 4) << 2);
#pragma unroll
        for (int n = 0; n < 4; ++n) {
            int col = n0 + wc * 64 + n * 16 + (lane & 15);
#pragma unroll
            for (int r = 0; r < 4; ++r) {
                if constexpr (F16OUT)
                    ((f16*)Cv)[(size_t)(row + r) * N + col] = (f16)acc[m][n][r];
                else
                    ((float*)Cv)[(size_t)(row + r) * N + col] = acc[m][n][r];
            }
        }
    }
#undef QSTAGE
#undef QCOMPUTE
}

// ---------------- RMSNorm + RoPE for q and k; one wave per (b,s,head) -------
__global__ __launch_bounds__(256) void rmsrope_k(const f16* __restrict__ qkvh,
                                                 const float* __restrict__ cosb, const float* __restrict__ sinb,
                                                 const float* __restrict__ qnw, const float* __restrict__ knw,
                                                 f16* __restrict__ qr, f16* __restrict__ kr) {
    int wid = threadIdx.x >> 6, lane = threadIdx.x & 63;
    int task = blockIdx.x * 4 + wid;
    int slot = task % 12;
    int bs = task / 12;
    int b = bs >> 11, s = bs & 2047;
    const f16* src;
    const float* w;
    f16* dst;
    if (slot < 8) {
        src = qkvh + (size_t)bs * 4096 + slot * 256;
        w = qnw;
        dst = qr + ((size_t)(b * 8 + slot) * 2048 + s) * 256;
    } else {
        int h = slot - 8;
        src = qkvh + (size_t)bs * 4096 + 2048 + h * 256;
        w = knw;
        dst = kr + ((size_t)(b * 4 + h) * 2048 + s) * 256;
    }
    int i = lane * 4;
    f16x4 xr = *(const f16x4*)(src + i);
    float4 x;
    x.x = (float)xr[0]; x.y = (float)xr[1]; x.z = (float)xr[2]; x.w = (float)xr[3];
    float ss = x.x * x.x + x.y * x.y + x.z * x.z + x.w * x.w;
#pragma unroll
    for (int o = 32; o; o >>= 1) ss += __shfl_xor(ss, o, 64);
    float rs = rsqrtf(ss * (1.0f / 256.0f) + 1e-6f);
    float4 y;
    y.x = __shfl_xor(x.x, 32, 64);
    y.y = __shfl_xor(x.y, 32, 64);
    y.z = __shfl_xor(x.z, 32, 64);
    y.w = __shfl_xor(x.w, 32, 64);
    float4 wv = *(const float4*)(w + i);
    float4 wp = *(const float4*)(w + (i ^ 128));
    float4 c = *(const float4*)(cosb + (size_t)bs * 256 + i);
    float4 sn = *(const float4*)(sinb + (size_t)bs * 256 + i);
    float sgn = (lane < 32) ? -1.0f : 1.0f;
    float n0 = x.x * rs * (1.f + wv.x), n1 = x.y * rs * (1.f + wv.y);
    float n2 = x.z * rs * (1.f + wv.z), n3 = x.w * rs * (1.f + wv.w);
    float r0 = y.x * rs * (1.f + wp.x) * sgn, r1 = y.y * rs * (1.f + wp.y) * sgn;
    float r2 = y.z * rs * (1.f + wp.z) * sgn, r3 = y.w * rs * (1.f + wp.w) * sgn;
    float o0 = n0 * c.x + r0 * sn.x;
    float o1 = n1 * c.y + r1 * sn.y;
    float o2 = n2 * c.z + r2 * sn.z;
    float o3 = n3 * c.w + r3 * sn.w;
    f16x4 outv;
    outv[0] = (f16)o0; outv[1] = (f16)o1; outv[2] = (f16)o2; outv[3] = (f16)o3;
    *(f16x4*)(dst + i) = outv;
}

// ---------------- V: transpose via LDS -> vt[b][kvh][d][s] (f16) ------------
__global__ __launch_bounds__(256) void vtrans2(const f16* __restrict__ qkvh, f16* __restrict__ vt) {
    __shared__ __align__(16) char Ls[64 * 516];
    int tile = blockIdx.x;
    int st = tile & 31;
    int by = tile >> 5;
    int b = by >> 2, kvh = by & 3;
    int tid = threadIdx.x;
    int s0 = st * 64;
    const f16* src = qkvh + ((size_t)(b * 2048 + s0)) * 4096 + 3072 + kvh * 256;
#pragma unroll
    for (int it = 0; it < 8; ++it) {
        int idx = it * 256 + tid;
        int srow = idx >> 5;
        int col8 = (idx & 31) * 8;
        f16x8 x = *(const f16x8*)(src + (size_t)srow * 4096 + col8);
        char* lp = Ls + srow * 516 + col8 * 2;
        *(f16x2*)(lp)      = f16x2{x[0], x[1]};
        *(f16x2*)(lp + 4)  = f16x2{x[2], x[3]};
        *(f16x2*)(lp + 8)  = f16x2{x[4], x[5]};
        *(f16x2*)(lp + 12) = f16x2{x[6], x[7]};
    }
    __syncthreads();
    f16* dst = vt + ((size_t)(by * 256) * 2048) + s0;
#pragma unroll
    for (int p = 0; p < 8; ++p) {
        int d = p * 32 + (tid >> 3);
        int s8 = (tid & 7) * 8;
        f16x8 o;
#pragma unroll
        for (int j = 0; j < 8; ++j)
            o[j] = *(const f16*)(Ls + (s8 + j) * 516 + d * 2);
        *(f16x8*)(dst + (size_t)d * 2048 + s8) = o;
    }
}

// ============ fused scores+softcap+mask+softmax+probs-write+PV ==============
// grid (32 qt, 16 bh), 256 thr (4 waves; wave w owns q-rows qt*64+w*16..+15).
// All LDS tiles XOR-swizzled: f(row, byte) = byte ^ ((row&7)<<4) (T2 / G4).
// K,V staged via gld16 with pre-swizzled GLOBAL source (rule #21); P tile
// scatter-written with swizzle, read back as MFMA A-frags conflict-free.
__global__ __launch_bounds__(256) void attn_fused(const f16* __restrict__ qr, const f16* __restrict__ kr,
                                                  const f16* __restrict__ vt, float* __restrict__ probs,
                                                  f16* __restrict__ attn) {
    int qt = blockIdx.x, bh = blockIdx.y;
    int b = bh >> 3, h = bh & 7;
    int tid = threadIdx.x, lane = tid & 63, w = tid >> 6;
    int g = lane >> 4;                       // k-group 0..3
    __shared__ __align__(16) char lds[40960];
    char* kvb = lds;                         // 32 KB: K stage, then V stage
    char* plb = lds + 32768;                 // 8 KB: P tile [64 rows][64 f16]

    // ---- Q fragments (global, read once) ----
    const f16* qbase = qr + ((size_t)bh * 2048 + qt * 64 + w * 16 + (lane & 15)) * 256 + g * 8;
    f16x8 af[8];
#pragma unroll
    for (int ks = 0; ks < 8; ++ks) af[ks] = *(const f16x8*)(qbase + ks * 32);

    // ---- phase A: QK^T band (9 k-tiles), swizzled K staging ----
    f32x4 acc[9][4] = {};
    const f16* kb0 = kr + ((size_t)((b * 4 + (h >> 1)) * 2048)) * 256;
#pragma unroll
    for (int kt = 0; kt < 9; ++kt) {
        int kta = qt - 8 + kt;
        if (kta >= 0) {
            const f16* kbase = kb0 + (size_t)kta * 64 * 256;
#pragma unroll
            for (int is = 0; is < 8; ++is) {
                int off = is * 4096 + w * 1024 + lane * 16;
                int row = off >> 9;
                int cb = off & 511;
                int sb = cb ^ ((row & 7) << 4);          // pre-swizzled source
                gld16(kbase + (size_t)row * 256 + (sb >> 1), kvb + off);
            }
            __syncthreads();
            __builtin_amdgcn_s_setprio(1);
#pragma unroll
            for (int n = 0; n < 4; ++n) {
                int row2 = n * 16 + (lane & 15);
#pragma unroll
                for (int ks = 0; ks < 8; ++ks) {
                    int cb = (ks * 64 + g * 16) ^ ((row2 & 7) << 4);
                    f16x8 bfr = *(const f16x8*)(kvb + row2 * 512 + cb);
                    acc[kt][n] = MFMA16(af[ks], bfr, acc[kt][n]);
                }
            }
            __builtin_amdgcn_s_setprio(0);
            __syncthreads();
        }
    }

    // ---- phase B: softcap + mask + softmax -> normalized f16 ph ----
    int row_l = w * 16 + (g << 2);
    int row_g0 = qt * 64 + row_l;
    f32x4 mx = {-1e30f, -1e30f, -1e30f, -1e30f};
#pragma unroll
    for (int kt = 0; kt < 9; ++kt) {
        int kta = qt - 8 + kt;
#pragma unroll
        for (int n = 0; n < 4; ++n) {
            int col = kta * 64 + n * 16 + (lane & 15);
#pragma unroll
            for (int r = 0; r < 4; ++r) {
                float s = acc[kt][n][r] * 0.0625f;
                float t = __expf(s * 0.04f);
                float v = 50.0f * (t - 1.0f) / (t + 1.0f);
                int rowg = row_g0 + r;
                bool ok = (kta >= 0) && (col <= rowg) && (rowg - col < 512);
                float pv_ = ok ? v : -1e9f;
                acc[kt][n][r] = pv_;
                mx[r] = fmaxf(mx[r], pv_);
            }
        }
    }
#pragma unroll
    for (int o = 1; o < 16; o <<= 1) {
#pragma unroll
        for (int r = 0; r < 4; ++r) mx[r] = fmaxf(mx[r], __shfl_xor(mx[r], o, 64));
    }
    f32x4 sm = {0.f, 0.f, 0.f, 0.f};
#pragma unroll
    for (int kt = 0; kt < 9; ++kt)
#pragma unroll
        for (int n = 0; n < 4; ++n)
#pragma unroll
            for (int r = 0; r < 4; ++r) {
                float e = __expf(acc[kt][n][r] - mx[r]);
                acc[kt][n][r] = e;
                sm[r] += e;
            }
#pragma unroll
    for (int o = 1; o < 16; o <<= 1) {
#pragma unroll
        for (int r = 0; r < 4; ++r) sm[r] += __shfl_xor(sm[r], o, 64);
    }
    f32x4 inv;
#pragma unroll
    for (int r = 0; r < 4; ++r) inv[r] = 1.0f / sm[r];
    f16x4 ph[9][4];
#pragma unroll
    for (int kt = 0; kt < 9; ++kt)
#pragma unroll
        for (int n = 0; n < 4; ++n)
#pragma unroll
            for (int r = 0; r < 4; ++r)
                ph[kt][n][r] = (f16)(acc[kt][n][r] * inv[r]);

    // ---- phase C+D: per k-tile {stage V, P->LDS, probs stores, PV MFMA} ----
    const f16* vtb = vt + (size_t)((b * 4 + (h >> 1)) * 256) * 2048;
    f32x4 pacc[16] = {};
#pragma unroll
    for (int kt = 0; kt < 9; ++kt) {
        int kta = qt - 8 + kt;
        if (kta < 0) continue;                         // block-uniform
        // stage V[kta]: Vs[d 0..255][k 0..63] f16, pre-swizzled source
#pragma unroll
        for (int is = 0; is < 8; ++is) {
            int off = is * 4096 + w * 1024 + lane * 16;
            int d = off >> 7;
            int cb = off & 127;
            int sb = cb ^ ((d & 7) << 4);
            gld16(vtb + (size_t)d * 2048 + kta * 64 + (sb >> 1), kvb + off);
        }
        // P tile -> LDS (swizzled scatter; 2-way bank = free)
#pragma unroll
        for (int n = 0; n < 4; ++n)
#pragma unroll
            for (int r = 0; r < 4; ++r) {
                int row = row_l + r;
                int cb = (n * 16 + (lane & 15)) * 2;
                *(f16*)(plb + row * 128 + (cb ^ ((row & 7) << 4))) = ph[kt][n][r];
            }
        // probs band stores (overlap with V DMA + MFMA)
#pragma unroll
        for (int n = 0; n < 4; ++n) {
            int col = kta * 64 + n * 16 + (lane & 15);
#pragma unroll
            for (int r = 0; r < 4; ++r)
                probs[((size_t)bh * 2048 + row_g0 + r) * 2048 + col] = (float)ph[kt][n][r];
        }
        __syncthreads();
        // PV: A-frags from P_lds, B-frags from Vs (both swizzled)
        int rowp = w * 16 + (lane & 15);
        int pswz = (rowp & 7) << 4;
        f16x8 a0 = *(const f16x8*)(plb + rowp * 128 + ((g * 16) ^ pswz));
        f16x8 a1 = *(const f16x8*)(plb + rowp * 128 + ((g * 16 + 64) ^ pswz));
        __builtin_amdgcn_s_setprio(1);
#pragma unroll
        for (int n = 0; n < 16; ++n) {
            int d = n * 16 + (lane & 15);
            int vswz = (d & 7) << 4;
            f16x8 b0 = *(const f16x8*)(kvb + d * 128 + ((g * 16) ^ vswz));
            f16x8 b1 = *(const f16x8*)(kvb + d * 128 + ((g * 16 + 64) ^ vswz));
            pacc[n] = MFMA16(a0, b0, pacc[n]);
            pacc[n] = MFMA16(a1, b1, pacc[n]);
        }
        __builtin_amdgcn_s_setprio(0);
        __syncthreads();
    }

    // ---- zeros outside band ----
    int kt0 = qt > 8 ? qt - 8 : 0;
    int pre = kt0 * 64;
    int suf = (qt + 1) * 64;
    float4 z4 = make_float4(0.f, 0.f, 0.f, 0.f);
    for (int r = 0; r < 16; ++r) {
        float* rp = probs + ((size_t)bh * 2048 + qt * 64 + w * 16 + r) * 2048;
        for (int off = lane * 4; off < pre; off += 256) *(float4*)(rp + off) = z4;
        for (int off = suf + lane * 4; off < 2048; off += 256) *(float4*)(rp + off) = z4;
    }

    // ---- attn epilogue (f16) ----
    size_t obase = ((size_t)b * 2048 + qt * 64 + row_l) * 2048 + h * 256;
#pragma unroll
    for (int n = 0; n < 16; ++n) {
        int col = n * 16 + (lane & 15);
#pragma unroll
        for (int r = 0; r < 4; ++r)
            attn[obase + (size_t)r * 2048 + col] = (f16)pacc[n][r];
    }
}

extern "C" void kernel_launch(void* const* d_in, const int* in_sizes, int n_in,
                              void* d_out, int out_size, void* d_ws, size_t ws_size,
                              hipStream_t stream) {
    (void)in_sizes; (void)n_in; (void)out_size; (void)ws_size;
    const float* hs   = (const float*)d_in[0];
    const float* cosb = (const float*)d_in[1];
    const float* sinb = (const float*)d_in[2];
    const float* qw   = (const float*)d_in[4];
    const float* kw   = (const float*)d_in[5];
    const float* vw   = (const float*)d_in[6];
    const float* ow   = (const float*)d_in[7];
    const float* qnw  = (const float*)d_in[8];
    const float* knw  = (const float*)d_in[9];

    float* out = (float*)d_out;
    float* probs = out + (size_t)2 * 2048 * 2560;          // output 1

    char* ws = (char*)d_ws;
    f16* hsb  = (f16*)(ws);                                // 20,971,520 B
    f16* wqkv = (f16*)(ws + 20971520);                     // 20,971,520 B
    f16* owb  = (f16*)(ws + 41943040);                     // 10,485,760 B
    f16* qkvh = (f16*)(ws + 52428800);                     // 33,554,432 B
    f16* qr   = (f16*)(ws + 85983232);                     // 16,777,216 B
    f16* kr   = (f16*)(ws + 102760448);                    //  8,388,608 B
    f16* vt   = (f16*)(ws + 111149056);                    //  8,388,608 B
    f16* attn = (f16*)(ws + 119537664);                    // 16,777,216 B

    // all fp32 -> fp16 casts in one launch
    cvt_all<<<12800, 256, 0, stream>>>(hs, qw, kw, vw, ow, hsb, wqkv, owb);

    // fused QKV projection: 256^2 deep-pipelined, f16 out
    gemm256<2560, 4096, 16, true><<<256, 512, 0, stream>>>(hsb, wqkv, qkvh);

    // RMSNorm + RoPE; V transpose (LDS-tiled)
    rmsrope_k<<<12288, 256, 0, stream>>>(qkvh, cosb, sinb, qnw, knw, qr, kr);
    vtrans2<<<256, 256, 0, stream>>>(qkvh, vt);

    // fused scores+softmax+probs+PV (swizzled LDS throughout)
    attn_fused<<<dim3(32, 16), 256, 0, stream>>>(qr, kr, vt, probs, attn);

    // O projection: 256^2 deep-pipelined, f32 out (output 0)
    gemm256<2048, 2560, 10, false><<<160, 512, 0, stream>>>(attn, owb, out);
}

// Round 7
// 343.939 us; speedup vs baseline: 1.2782x; 1.0353x over previous
//
#include <hip/hip_runtime.h>

typedef _Float16 f16;
typedef float f32x4 __attribute__((ext_vector_type(4)));
typedef _Float16 f16x8 __attribute__((ext_vector_type(8)));
typedef _Float16 f16x4 __attribute__((ext_vector_type(4)));
typedef _Float16 f16x2 __attribute__((ext_vector_type(2)));

#define MFMA16(a, b, c) __builtin_amdgcn_mfma_f32_16x16x32_f16((a), (b), (c), 0, 0, 0)

__device__ __forceinline__ void gld16(const void* g, void* l) {
    __builtin_amdgcn_global_load_lds((const __attribute__((address_space(1))) unsigned int*)g,
                                     (__attribute__((address_space(3))) unsigned int*)l, 16, 0, 0);
}

// ---------------- merged fp32 -> fp16 cast for all 5 tensors ----------------
__global__ __launch_bounds__(256) void cvt_all(const float* __restrict__ hs, const float* __restrict__ qw,
                                               const float* __restrict__ kw, const float* __restrict__ vw,
                                               const float* __restrict__ ow, f16* __restrict__ hsb,
                                               f16* __restrict__ wqkv, f16* __restrict__ owb) {
    long g = (long)(blockIdx.x * 256 + threadIdx.x) * 8;
    const float* src;
    f16* dst;
    long off;
    if (g < 10485760L) { src = hs; dst = hsb; off = g; }
    else if (g < 15728640L) { src = qw; dst = wqkv; off = g - 10485760L; }
    else if (g < 18350080L) { src = kw; dst = wqkv + 5242880; off = g - 15728640L; }
    else if (g < 20971520L) { src = vw; dst = wqkv + 7864320; off = g - 18350080L; }
    else { src = ow; dst = owb; off = g - 20971520L; }
    float4 a = *(const float4*)(src + off);
    float4 b = *(const float4*)(src + off + 4);
    f16x8 o;
    o[0] = (f16)a.x; o[1] = (f16)a.y; o[2] = (f16)a.z; o[3] = (f16)a.w;
    o[4] = (f16)b.x; o[5] = (f16)b.y; o[6] = (f16)b.z; o[7] = (f16)b.w;
    *(f16x8*)(dst + off) = o;
}

// ============ 256x256-tile deep-pipelined GEMM (T1+T2+T4+T5) ================
template <int K, int N, int GN, bool F16OUT>
__global__ __launch_bounds__(512, 1) void gemm256(const f16* __restrict__ A, const f16* __restrict__ W,
                                                  void* __restrict__ Cv) {
    constexpr int NT = K / 32;
    __shared__ __align__(16) char lds[131072];
    const int tid = threadIdx.x;
    const int lane = tid & 63, wid = tid >> 6;
    const int wr = wid >> 2, wc = wid & 3;
    int bid = blockIdx.x;
    int swz = (bid & 7) * ((16 * GN) >> 3) + (bid >> 3);
    const int m0 = (swz / GN) * 256, n0 = (swz % GN) * 256;

    const int kel = 8 * ((tid & 3) ^ ((tid >> 2) & 3));
    const f16* pA0 = A + (size_t)(m0 + (tid >> 2)) * K + kel;
    const f16* pA1 = pA0 + (size_t)128 * K;
    const f16* pB0 = W + (size_t)(n0 + (tid >> 2)) * K + kel;
    const f16* pB1 = pB0 + (size_t)128 * K;
    const int dst_o = tid * 16;

#define QSTAGE(bi, t)                                                     \
    {                                                                     \
        char* ab_ = lds + (bi) * 32768;                                   \
        int k0_ = (t) * 32;                                               \
        gld16(pA0 + k0_, ab_ + dst_o);                                    \
        gld16(pA1 + k0_, ab_ + 8192 + dst_o);                             \
        gld16(pB0 + k0_, ab_ + 16384 + dst_o);                            \
        gld16(pB1 + k0_, ab_ + 24576 + dst_o);                            \
    }

    const int ccx = (((lane >> 4) << 4) ^ ((lane & 3) << 4));
    const int ar = wr * 128 + (lane & 15);
    const int br = wc * 64 + (lane & 15);

    f32x4 acc[8][4] = {};

#define QCOMPUTE(bi)                                                      \
    {                                                                     \
        const char* ab_ = lds + (bi) * 32768;                             \
        const char* bb_ = ab_ + 16384;                                    \
        f16x8 Af[8], Bf[4];                                               \
        _Pragma("unroll")                                                 \
        for (int m = 0; m < 8; ++m)                                       \
            Af[m] = *(const f16x8*)(ab_ + (ar + m * 16) * 64 + ccx);      \
        _Pragma("unroll")                                                 \
        for (int n = 0; n < 4; ++n)                                       \
            Bf[n] = *(const f16x8*)(bb_ + (br + n * 16) * 64 + ccx);      \
        __builtin_amdgcn_s_setprio(1);                                    \
        _Pragma("unroll")                                                 \
        for (int m = 0; m < 8; ++m)                                       \
            _Pragma("unroll")                                             \
            for (int n = 0; n < 4; ++n)                                   \
                acc[m][n] = MFMA16(Af[m], Bf[n], acc[m][n]);              \
        __builtin_amdgcn_s_setprio(0);                                    \
    }

    QSTAGE(0, 0)
    QSTAGE(1, 1)
    QSTAGE(2, 2)
    asm volatile("s_waitcnt vmcnt(8)" ::: "memory");
    __builtin_amdgcn_s_barrier();

#pragma unroll 1
    for (int t = 0; t < NT - 3; ++t) {
        QCOMPUTE(t & 3)
        asm volatile("s_waitcnt lgkmcnt(0)" ::: "memory");
        __builtin_amdgcn_s_barrier();
        QSTAGE((t + 3) & 3, t + 3)
        asm volatile("s_waitcnt vmcnt(8)" ::: "memory");
        __builtin_amdgcn_s_barrier();
    }
    QCOMPUTE((NT - 3) & 3)
    asm volatile("s_waitcnt lgkmcnt(0)" ::: "memory");
    __builtin_amdgcn_s_barrier();
    asm volatile("s_waitcnt vmcnt(4)" ::: "memory");
    __builtin_amdgcn_s_barrier();
    QCOMPUTE((NT - 2) & 3)
    asm volatile("s_waitcnt lgkmcnt(0)" ::: "memory");
    __builtin_amdgcn_s_barrier();
    asm volatile("s_waitcnt vmcnt(0)" ::: "memory");
    __builtin_amdgcn_s_barrier();
    QCOMPUTE((NT - 1) & 3)

#pragma unroll
    for (int m = 0; m < 8; ++m) {
        int row = m0 + wr * 128 + m * 16 + ((lane >> 4) << 2);
#pragma unroll
        for (int n = 0; n < 4; ++n) {
            int col = n0 + wc * 64 + n * 16 + (lane & 15);
#pragma unroll
            for (int r = 0; r < 4; ++r) {
                if constexpr (F16OUT)
                    ((f16*)Cv)[(size_t)(row + r) * N + col] = (f16)acc[m][n][r];
                else
                    ((float*)Cv)[(size_t)(row + r) * N + col] = acc[m][n][r];
            }
        }
    }
#undef QSTAGE
#undef QCOMPUTE
}

// ---------------- RMSNorm + RoPE for q and k; one wave per (b,s,head) -------
__global__ __launch_bounds__(256) void rmsrope_k(const f16* __restrict__ qkvh,
                                                 const float* __restrict__ cosb, const float* __restrict__ sinb,
                                                 const float* __restrict__ qnw, const float* __restrict__ knw,
                                                 f16* __restrict__ qr, f16* __restrict__ kr) {
    int wid = threadIdx.x >> 6, lane = threadIdx.x & 63;
    int task = blockIdx.x * 4 + wid;
    int slot = task % 12;
    int bs = task / 12;
    int b = bs >> 11, s = bs & 2047;
    const f16* src;
    const float* w;
    f16* dst;
    if (slot < 8) {
        src = qkvh + (size_t)bs * 4096 + slot * 256;
        w = qnw;
        dst = qr + ((size_t)(b * 8 + slot) * 2048 + s) * 256;
    } else {
        int h = slot - 8;
        src = qkvh + (size_t)bs * 4096 + 2048 + h * 256;
        w = knw;
        dst = kr + ((size_t)(b * 4 + h) * 2048 + s) * 256;
    }
    int i = lane * 4;
    f16x4 xr = *(const f16x4*)(src + i);
    float4 x;
    x.x = (float)xr[0]; x.y = (float)xr[1]; x.z = (float)xr[2]; x.w = (float)xr[3];
    float ss = x.x * x.x + x.y * x.y + x.z * x.z + x.w * x.w;
#pragma unroll
    for (int o = 32; o; o >>= 1) ss += __shfl_xor(ss, o, 64);
    float rs = rsqrtf(ss * (1.0f / 256.0f) + 1e-6f);
    float4 y;
    y.x = __shfl_xor(x.x, 32, 64);
    y.y = __shfl_xor(x.y, 32, 64);
    y.z = __shfl_xor(x.z, 32, 64);
    y.w = __shfl_xor(x.w, 32, 64);
    float4 wv = *(const float4*)(w + i);
    float4 wp = *(const float4*)(w + (i ^ 128));
    float4 c = *(const float4*)(cosb + (size_t)bs * 256 + i);
    float4 sn = *(const float4*)(sinb + (size_t)bs * 256 + i);
    float sgn = (lane < 32) ? -1.0f : 1.0f;
    float n0 = x.x * rs * (1.f + wv.x), n1 = x.y * rs * (1.f + wv.y);
    float n2 = x.z * rs * (1.f + wv.z), n3 = x.w * rs * (1.f + wv.w);
    float r0 = y.x * rs * (1.f + wp.x) * sgn, r1 = y.y * rs * (1.f + wp.y) * sgn;
    float r2 = y.z * rs * (1.f + wp.z) * sgn, r3 = y.w * rs * (1.f + wp.w) * sgn;
    float o0 = n0 * c.x + r0 * sn.x;
    float o1 = n1 * c.y + r1 * sn.y;
    float o2 = n2 * c.z + r2 * sn.z;
    float o3 = n3 * c.w + r3 * sn.w;
    f16x4 outv;
    outv[0] = (f16)o0; outv[1] = (f16)o1; outv[2] = (f16)o2; outv[3] = (f16)o3;
    *(f16x4*)(dst + i) = outv;
}

// ---------------- V: transpose via LDS -> vt[b][kvh][d][s] (f16) ------------
__global__ __launch_bounds__(256) void vtrans2(const f16* __restrict__ qkvh, f16* __restrict__ vt) {
    __shared__ __align__(16) char Ls[64 * 516];
    int tile = blockIdx.x;
    int st = tile & 31;
    int by = tile >> 5;
    int b = by >> 2, kvh = by & 3;
    int tid = threadIdx.x;
    int s0 = st * 64;
    const f16* src = qkvh + ((size_t)(b * 2048 + s0)) * 4096 + 3072 + kvh * 256;
#pragma unroll
    for (int it = 0; it < 8; ++it) {
        int idx = it * 256 + tid;
        int srow = idx >> 5;
        int col8 = (idx & 31) * 8;
        f16x8 x = *(const f16x8*)(src + (size_t)srow * 4096 + col8);
        char* lp = Ls + srow * 516 + col8 * 2;
        *(f16x2*)(lp)      = f16x2{x[0], x[1]};
        *(f16x2*)(lp + 4)  = f16x2{x[2], x[3]};
        *(f16x2*)(lp + 8)  = f16x2{x[4], x[5]};
        *(f16x2*)(lp + 12) = f16x2{x[6], x[7]};
    }
    __syncthreads();
    f16* dst = vt + ((size_t)(by * 256) * 2048) + s0;
#pragma unroll
    for (int p = 0; p < 8; ++p) {
        int d = p * 32 + (tid >> 3);
        int s8 = (tid & 7) * 8;
        f16x8 o;
#pragma unroll
        for (int j = 0; j < 8; ++j)
            o[j] = *(const f16*)(Ls + (s8 + j) * 516 + d * 2);
        *(f16x8*)(dst + (size_t)d * 2048 + s8) = o;
    }
}

// ============ fused scores+softcap+mask+softmax+probs-write+PV ==============
// grid (32 qt, 16 bh), 256 thr. K and V loops double-buffered with counted
// vmcnt(8) (T3/T4): stage t+1 overlaps MFMA t; no vmcnt(0) drain mid-loop.
__global__ __launch_bounds__(256) void attn_fused(const f16* __restrict__ qr, const f16* __restrict__ kr,
                                                  const f16* __restrict__ vt, float* __restrict__ probs,
                                                  f16* __restrict__ attn) {
    int qt = blockIdx.x, bh = blockIdx.y;
    int b = bh >> 3, h = bh & 7;
    int tid = threadIdx.x, lane = tid & 63, w = tid >> 6;
    int g = lane >> 4;
    __shared__ __align__(16) char lds[73728];   // 2x32KB K/V dbuf + 8KB P
    char* plb = lds + 65536;

    // ---- Q fragments (global, read once) ----
    const f16* qbase = qr + ((size_t)bh * 2048 + qt * 64 + w * 16 + (lane & 15)) * 256 + g * 8;
    f16x8 af[8];
#pragma unroll
    for (int ks = 0; ks < 8; ++ks) af[ks] = *(const f16x8*)(qbase + ks * 32);

    const int kt_first = (qt >= 8) ? 0 : (8 - qt);   // block-uniform
    const f16* kb0 = kr + ((size_t)((b * 4 + (h >> 1)) * 2048)) * 256;

#define KSTAGE(kta_, par_)                                                    \
    {                                                                         \
        const f16* kb_ = kb0 + (size_t)(kta_) * 16384;                        \
        char* db_ = lds + (par_) * 32768;                                     \
        _Pragma("unroll")                                                     \
        for (int is = 0; is < 8; ++is) {                                      \
            int off = is * 4096 + w * 1024 + lane * 16;                       \
            int row = off >> 9;                                               \
            int sb = (off & 511) ^ ((row & 7) << 4);                          \
            gld16(kb_ + row * 256 + (sb >> 1), db_ + off);                    \
        }                                                                     \
    }

    // ---- phase A: QK^T band, double-buffered K staging ----
    KSTAGE(qt - 8 + kt_first, kt_first & 1)
    f32x4 acc[9][4] = {};
#pragma unroll
    for (int kt = 0; kt < 9; ++kt) {
        int kta = qt - 8 + kt;
        if (kta >= 0) {
            if (kt < 8) {
                KSTAGE(kta + 1, (kt + 1) & 1)
                asm volatile("s_waitcnt vmcnt(8)" ::: "memory");
            } else {
                asm volatile("s_waitcnt vmcnt(0)" ::: "memory");
            }
            __builtin_amdgcn_s_barrier();
            __builtin_amdgcn_sched_barrier(0);
            const char* kbuf = lds + (kt & 1) * 32768;
            __builtin_amdgcn_s_setprio(1);
#pragma unroll
            for (int n = 0; n < 4; ++n) {
                int row2 = n * 16 + (lane & 15);
#pragma unroll
                for (int ks = 0; ks < 8; ++ks) {
                    int cb = (ks * 64 + g * 16) ^ ((row2 & 7) << 4);
                    f16x8 bfr = *(const f16x8*)(kbuf + row2 * 512 + cb);
                    acc[kt][n] = MFMA16(af[ks], bfr, acc[kt][n]);
                }
            }
            __builtin_amdgcn_s_setprio(0);
            __builtin_amdgcn_s_barrier();
        }
    }

    // ---- phase B: softcap + mask + softmax -> normalized f16 ph ----
    int row_l = w * 16 + (g << 2);
    int row_g0 = qt * 64 + row_l;
    f32x4 mx = {-1e30f, -1e30f, -1e30f, -1e30f};
#pragma unroll
    for (int kt = 0; kt < 9; ++kt) {
        int kta = qt - 8 + kt;
#pragma unroll
        for (int n = 0; n < 4; ++n) {
            int col = kta * 64 + n * 16 + (lane & 15);
#pragma unroll
            for (int r = 0; r < 4; ++r) {
                float s = acc[kt][n][r] * 0.0625f;
                float t = __expf(s * 0.04f);
                float v = 50.0f * (t - 1.0f) / (t + 1.0f);
                int rowg = row_g0 + r;
                bool ok = (kta >= 0) && (col <= rowg) && (rowg - col < 512);
                float pv_ = ok ? v : -1e9f;
                acc[kt][n][r] = pv_;
                mx[r] = fmaxf(mx[r], pv_);
            }
        }
    }
#pragma unroll
    for (int o = 1; o < 16; o <<= 1) {
#pragma unroll
        for (int r = 0; r < 4; ++r) mx[r] = fmaxf(mx[r], __shfl_xor(mx[r], o, 64));
    }
    f32x4 sm = {0.f, 0.f, 0.f, 0.f};
#pragma unroll
    for (int kt = 0; kt < 9; ++kt)
#pragma unroll
        for (int n = 0; n < 4; ++n)
#pragma unroll
            for (int r = 0; r < 4; ++r) {
                float e = __expf(acc[kt][n][r] - mx[r]);
                acc[kt][n][r] = e;
                sm[r] += e;
            }
#pragma unroll
    for (int o = 1; o < 16; o <<= 1) {
#pragma unroll
        for (int r = 0; r < 4; ++r) sm[r] += __shfl_xor(sm[r], o, 64);
    }
    f32x4 inv;
#pragma unroll
    for (int r = 0; r < 4; ++r) inv[r] = 1.0f / sm[r];
    f16x4 ph[9][4];
#pragma unroll
    for (int kt = 0; kt < 9; ++kt)
#pragma unroll
        for (int n = 0; n < 4; ++n)
#pragma unroll
            for (int r = 0; r < 4; ++r)
                ph[kt][n][r] = (f16)(acc[kt][n][r] * inv[r]);

    // ---- phase C: per k-tile PV, double-buffered V staging ----
    const f16* vtb = vt + (size_t)((b * 4 + (h >> 1)) * 256) * 2048;

#define VSTAGE(kta_, par_)                                                    \
    {                                                                         \
        char* db_ = lds + (par_) * 32768;                                     \
        _Pragma("unroll")                                                     \
        for (int is = 0; is < 8; ++is) {                                      \
            int off = is * 4096 + w * 1024 + lane * 16;                       \
            int d = off >> 7;                                                 \
            int sb = (off & 127) ^ ((d & 7) << 4);                            \
            gld16(vtb + (size_t)d * 2048 + (kta_) * 64 + (sb >> 1), db_ + off); \
        }                                                                     \
    }

    VSTAGE(qt - 8 + kt_first, kt_first & 1)
    f32x4 pacc[16] = {};
#pragma unroll
    for (int kt = 0; kt < 9; ++kt) {
        int kta = qt - 8 + kt;
        if (kta >= 0) {
            if (kt < 8) VSTAGE(kta + 1, (kt + 1) & 1)
            // P tile -> LDS (swizzled scatter)
#pragma unroll
            for (int n = 0; n < 4; ++n)
#pragma unroll
                for (int r = 0; r < 4; ++r) {
                    int row = row_l + r;
                    int cb = (n * 16 + (lane & 15)) * 2;
                    *(f16*)(plb + row * 128 + (cb ^ ((row & 7) << 4))) = ph[kt][n][r];
                }
            if (kt < 8) {
                asm volatile("s_waitcnt vmcnt(8) lgkmcnt(0)" ::: "memory");
            } else {
                asm volatile("s_waitcnt vmcnt(0) lgkmcnt(0)" ::: "memory");
            }
            __builtin_amdgcn_s_barrier();
            __builtin_amdgcn_sched_barrier(0);
            // probs band stores (drain under the MFMA below)
#pragma unroll
            for (int n = 0; n < 4; ++n) {
                int col = kta * 64 + n * 16 + (lane & 15);
#pragma unroll
                for (int r = 0; r < 4; ++r)
                    probs[((size_t)bh * 2048 + row_g0 + r) * 2048 + col] = (float)ph[kt][n][r];
            }
            const char* vbuf = lds + (kt & 1) * 32768;
            int rowp = w * 16 + (lane & 15);
            int pswz = (rowp & 7) << 4;
            f16x8 a0 = *(const f16x8*)(plb + rowp * 128 + ((g * 16) ^ pswz));
            f16x8 a1 = *(const f16x8*)(plb + rowp * 128 + ((g * 16 + 64) ^ pswz));
            __builtin_amdgcn_s_setprio(1);
#pragma unroll
            for (int n = 0; n < 16; ++n) {
                int d = n * 16 + (lane & 15);
                int vswz = (d & 7) << 4;
                f16x8 b0 = *(const f16x8*)(vbuf + d * 128 + ((g * 16) ^ vswz));
                f16x8 b1 = *(const f16x8*)(vbuf + d * 128 + ((g * 16 + 64) ^ vswz));
                pacc[n] = MFMA16(a0, b0, pacc[n]);
                pacc[n] = MFMA16(a1, b1, pacc[n]);
            }
            __builtin_amdgcn_s_setprio(0);
            __builtin_amdgcn_s_barrier();
        }
    }
#undef KSTAGE
#undef VSTAGE

    // ---- zeros outside band ----
    int kt0 = qt > 8 ? qt - 8 : 0;
    int pre = kt0 * 64;
    int suf = (qt + 1) * 64;
    float4 z4 = make_float4(0.f, 0.f, 0.f, 0.f);
    for (int r = 0; r < 16; ++r) {
        float* rp = probs + ((size_t)bh * 2048 + qt * 64 + w * 16 + r) * 2048;
        for (int off = lane * 4; off < pre; off += 256) *(float4*)(rp + off) = z4;
        for (int off = suf + lane * 4; off < 2048; off += 256) *(float4*)(rp + off) = z4;
    }

    // ---- attn epilogue (f16) ----
    size_t obase = ((size_t)b * 2048 + qt * 64 + row_l) * 2048 + h * 256;
#pragma unroll
    for (int n = 0; n < 16; ++n) {
        int col = n * 16 + (lane & 15);
#pragma unroll
        for (int r = 0; r < 4; ++r)
            attn[obase + (size_t)r * 2048 + col] = (f16)pacc[n][r];
    }
}

extern "C" void kernel_launch(void* const* d_in, const int* in_sizes, int n_in,
                              void* d_out, int out_size, void* d_ws, size_t ws_size,
                              hipStream_t stream) {
    (void)in_sizes; (void)n_in; (void)out_size; (void)ws_size;
    const float* hs   = (const float*)d_in[0];
    const float* cosb = (const float*)d_in[1];
    const float* sinb = (const float*)d_in[2];
    const float* qw   = (const float*)d_in[4];
    const float* kw   = (const float*)d_in[5];
    const float* vw   = (const float*)d_in[6];
    const float* ow   = (const float*)d_in[7];
    const float* qnw  = (const float*)d_in[8];
    const float* knw  = (const float*)d_in[9];

    float* out = (float*)d_out;
    float* probs = out + (size_t)2 * 2048 * 2560;          // output 1

    char* ws = (char*)d_ws;
    f16* hsb  = (f16*)(ws);                                // 20,971,520 B
    f16* wqkv = (f16*)(ws + 20971520);                     // 20,971,520 B
    f16* owb  = (f16*)(ws + 41943040);                     // 10,485,760 B
    f16* qkvh = (f16*)(ws + 52428800);                     // 33,554,432 B
    f16* qr   = (f16*)(ws + 85983232);                     // 16,777,216 B
    f16* kr   = (f16*)(ws + 102760448);                    //  8,388,608 B
    f16* vt   = (f16*)(ws + 111149056);                    //  8,388,608 B
    f16* attn = (f16*)(ws + 119537664);                    // 16,777,216 B

    // all fp32 -> fp16 casts in one launch
    cvt_all<<<12800, 256, 0, stream>>>(hs, qw, kw, vw, ow, hsb, wqkv, owb);

    // fused QKV projection: 256^2 deep-pipelined, f16 out
    gemm256<2560, 4096, 16, true><<<256, 512, 0, stream>>>(hsb, wqkv, qkvh);

    // RMSNorm + RoPE; V transpose (LDS-tiled)
    rmsrope_k<<<12288, 256, 0, stream>>>(qkvh, cosb, sinb, qnw, knw, qr, kr);
    vtrans2<<<256, 256, 0, stream>>>(qkvh, vt);

    // fused scores+softmax+probs+PV (dbuf K/V, counted vmcnt)
    attn_fused<<<dim3(32, 16), 256, 0, stream>>>(qr, kr, vt, probs, attn);

    // O projection: 256^2 deep-pipelined, f32 out (output 0)
    gemm256<2048, 2560, 10, false><<<160, 512, 0, stream>>>(attn, owb, out);
}

// Round 8
// 323.172 us; speedup vs baseline: 1.3603x; 1.0643x over previous
//
#include <hip/hip_runtime.h>

typedef _Float16 f16;
typedef float f32x4 __attribute__((ext_vector_type(4)));
typedef _Float16 f16x8 __attribute__((ext_vector_type(8)));
typedef _Float16 f16x4 __attribute__((ext_vector_type(4)));
typedef _Float16 f16x2 __attribute__((ext_vector_type(2)));

#define MFMA16(a, b, c) __builtin_amdgcn_mfma_f32_16x16x32_f16((a), (b), (c), 0, 0, 0)

__device__ __forceinline__ void gld16(const void* g, void* l) {
    __builtin_amdgcn_global_load_lds((const __attribute__((address_space(1))) unsigned int*)g,
                                     (__attribute__((address_space(3))) unsigned int*)l, 16, 0, 0);
}

// ---------------- merged fp32 -> fp16 cast for all 5 tensors ----------------
__global__ __launch_bounds__(256) void cvt_all(const float* __restrict__ hs, const float* __restrict__ qw,
                                               const float* __restrict__ kw, const float* __restrict__ vw,
                                               const float* __restrict__ ow, f16* __restrict__ hsb,
                                               f16* __restrict__ wqkv, f16* __restrict__ owb) {
    long g = (long)(blockIdx.x * 256 + threadIdx.x) * 8;
    const float* src;
    f16* dst;
    long off;
    if (g < 10485760L) { src = hs; dst = hsb; off = g; }
    else if (g < 15728640L) { src = qw; dst = wqkv; off = g - 10485760L; }
    else if (g < 18350080L) { src = kw; dst = wqkv + 5242880; off = g - 15728640L; }
    else if (g < 20971520L) { src = vw; dst = wqkv + 7864320; off = g - 18350080L; }
    else { src = ow; dst = owb; off = g - 20971520L; }
    float4 a = *(const float4*)(src + off);
    float4 b = *(const float4*)(src + off + 4);
    f16x8 o;
    o[0] = (f16)a.x; o[1] = (f16)a.y; o[2] = (f16)a.z; o[3] = (f16)a.w;
    o[4] = (f16)b.x; o[5] = (f16)b.y; o[6] = (f16)b.z; o[7] = (f16)b.w;
    *(f16x8*)(dst + off) = o;
}

// ============ 256x256-tile GEMM, BK=64, 2-buf, 1 barrier/K-tile (T1-T5) =====
// C[4096,N] = A[4096,K] * W[N,K]^T, f16 in, f16/f32 out. 512 thr = 8 waves.
// LDS: 2 x (A 32K | B 32K) = 128 KiB. Stage(t+1) issued BEFORE compute(t);
// single combined vmcnt(0)+lgkmcnt(0) drain + s_barrier per 64-K tile
// (loads get the whole ~2500-cyc compute phase to land).
// Swizzle (128B rows): stored byte cb ^ ((row&7)<<4); global source
// pre-swizzled via kel = 8*((tid&7)^((tid>>3)&7))  (rule #21 both-sides).
template <int K, int N, int GN, bool F16OUT>
__global__ __launch_bounds__(512, 1) void gemm256(const f16* __restrict__ A, const f16* __restrict__ W,
                                                  void* __restrict__ Cv) {
    constexpr int NT = K / 64;
    __shared__ __align__(16) char lds[131072];
    const int tid = threadIdx.x;
    const int lane = tid & 63, wid = tid >> 6;
    const int wr = wid >> 2, wc = wid & 3;
    const int g = lane >> 4;
    int bid = blockIdx.x;
    int swz = (bid & 7) * ((16 * GN) >> 3) + (bid >> 3);
    const int m0 = (swz / GN) * 256, n0 = (swz % GN) * 256;

    const int kel = 8 * ((tid & 7) ^ ((tid >> 3) & 7));   // pre-swizzled k (elems)
    const int rowb = tid >> 3;                            // 0..63
    const f16* pA = A + (size_t)(m0 + rowb) * K + kel;
    const f16* pB = W + (size_t)(n0 + rowb) * K + kel;
    const int dst_o = tid * 16;

#define QSTAGE(bi, t)                                                     \
    {                                                                     \
        char* lb_ = lds + (bi) * 65536;                                   \
        int k0_ = (t) * 64;                                               \
        gld16(pA + k0_,                 lb_ + dst_o);                     \
        gld16(pA + (size_t)64 * K + k0_,  lb_ + 8192 + dst_o);            \
        gld16(pA + (size_t)128 * K + k0_, lb_ + 16384 + dst_o);           \
        gld16(pA + (size_t)192 * K + k0_, lb_ + 24576 + dst_o);           \
        gld16(pB + k0_,                 lb_ + 32768 + dst_o);             \
        gld16(pB + (size_t)64 * K + k0_,  lb_ + 40960 + dst_o);           \
        gld16(pB + (size_t)128 * K + k0_, lb_ + 49152 + dst_o);           \
        gld16(pB + (size_t)192 * K + k0_, lb_ + 57344 + dst_o);           \
    }

    const int xorv = (lane & 7) << 4;
    const int arow = wr * 128 + (lane & 15);
    const int brow = wc * 64 + (lane & 15);

    f32x4 acc[8][4] = {};

#define QCOMPUTE(bi)                                                      \
    {                                                                     \
        const char* ab_ = lds + (bi) * 65536;                             \
        const char* bb_ = ab_ + 32768;                                    \
        _Pragma("unroll")                                                 \
        for (int ks = 0; ks < 2; ++ks) {                                  \
            const int cc = (ks * 64 + g * 16) ^ xorv;                     \
            f16x8 Af[8], Bf[4];                                           \
            _Pragma("unroll")                                             \
            for (int m = 0; m < 8; ++m)                                   \
                Af[m] = *(const f16x8*)(ab_ + (arow + m * 16) * 128 + cc);\
            _Pragma("unroll")                                             \
            for (int n = 0; n < 4; ++n)                                   \
                Bf[n] = *(const f16x8*)(bb_ + (brow + n * 16) * 128 + cc);\
            __builtin_amdgcn_s_setprio(1);                                \
            _Pragma("unroll")                                             \
            for (int m = 0; m < 8; ++m)                                   \
                _Pragma("unroll")                                         \
                for (int n = 0; n < 4; ++n)                               \
                    acc[m][n] = MFMA16(Af[m], Bf[n], acc[m][n]);          \
            __builtin_amdgcn_s_setprio(0);                                \
        }                                                                 \
    }

    QSTAGE(0, 0)
    asm volatile("s_waitcnt vmcnt(0)" ::: "memory");
    __builtin_amdgcn_s_barrier();

#pragma unroll 1
    for (int t = 0; t < NT; ++t) {
        if (t + 1 < NT) QSTAGE((t + 1) & 1, t + 1)   // issue-early (T14/T3)
        QCOMPUTE(t & 1)
        asm volatile("s_waitcnt vmcnt(0) lgkmcnt(0)" ::: "memory");
        __builtin_amdgcn_s_barrier();                // one barrier per K-tile
    }

#pragma unroll
    for (int m = 0; m < 8; ++m) {
        int row = m0 + wr * 128 + m * 16 + ((lane >> 4) << 2);
#pragma unroll
        for (int n = 0; n < 4; ++n) {
            int col = n0 + wc * 64 + n * 16 + (lane & 15);
#pragma unroll
            for (int r = 0; r < 4; ++r) {
                if constexpr (F16OUT)
                    ((f16*)Cv)[(size_t)(row + r) * N + col] = (f16)acc[m][n][r];
                else
                    ((float*)Cv)[(size_t)(row + r) * N + col] = acc[m][n][r];
            }
        }
    }
#undef QSTAGE
#undef QCOMPUTE
}

// ---------------- RMSNorm + RoPE for q and k; one wave per (b,s,head) -------
__global__ __launch_bounds__(256) void rmsrope_k(const f16* __restrict__ qkvh,
                                                 const float* __restrict__ cosb, const float* __restrict__ sinb,
                                                 const float* __restrict__ qnw, const float* __restrict__ knw,
                                                 f16* __restrict__ qr, f16* __restrict__ kr) {
    int wid = threadIdx.x >> 6, lane = threadIdx.x & 63;
    int task = blockIdx.x * 4 + wid;
    int slot = task % 12;
    int bs = task / 12;
    int b = bs >> 11, s = bs & 2047;
    const f16* src;
    const float* w;
    f16* dst;
    if (slot < 8) {
        src = qkvh + (size_t)bs * 4096 + slot * 256;
        w = qnw;
        dst = qr + ((size_t)(b * 8 + slot) * 2048 + s) * 256;
    } else {
        int h = slot - 8;
        src = qkvh + (size_t)bs * 4096 + 2048 + h * 256;
        w = knw;
        dst = kr + ((size_t)(b * 4 + h) * 2048 + s) * 256;
    }
    int i = lane * 4;
    f16x4 xr = *(const f16x4*)(src + i);
    float4 x;
    x.x = (float)xr[0]; x.y = (float)xr[1]; x.z = (float)xr[2]; x.w = (float)xr[3];
    float ss = x.x * x.x + x.y * x.y + x.z * x.z + x.w * x.w;
#pragma unroll
    for (int o = 32; o; o >>= 1) ss += __shfl_xor(ss, o, 64);
    float rs = rsqrtf(ss * (1.0f / 256.0f) + 1e-6f);
    float4 y;
    y.x = __shfl_xor(x.x, 32, 64);
    y.y = __shfl_xor(x.y, 32, 64);
    y.z = __shfl_xor(x.z, 32, 64);
    y.w = __shfl_xor(x.w, 32, 64);
    float4 wv = *(const float4*)(w + i);
    float4 wp = *(const float4*)(w + (i ^ 128));
    float4 c = *(const float4*)(cosb + (size_t)bs * 256 + i);
    float4 sn = *(const float4*)(sinb + (size_t)bs * 256 + i);
    float sgn = (lane < 32) ? -1.0f : 1.0f;
    float n0 = x.x * rs * (1.f + wv.x), n1 = x.y * rs * (1.f + wv.y);
    float n2 = x.z * rs * (1.f + wv.z), n3 = x.w * rs * (1.f + wv.w);
    float r0 = y.x * rs * (1.f + wp.x) * sgn, r1 = y.y * rs * (1.f + wp.y) * sgn;
    float r2 = y.z * rs * (1.f + wp.z) * sgn, r3 = y.w * rs * (1.f + wp.w) * sgn;
    float o0 = n0 * c.x + r0 * sn.x;
    float o1 = n1 * c.y + r1 * sn.y;
    float o2 = n2 * c.z + r2 * sn.z;
    float o3 = n3 * c.w + r3 * sn.w;
    f16x4 outv;
    outv[0] = (f16)o0; outv[1] = (f16)o1; outv[2] = (f16)o2; outv[3] = (f16)o3;
    *(f16x4*)(dst + i) = outv;
}

// ---------------- V: transpose via LDS -> vt[b][kvh][d][s] (f16) ------------
__global__ __launch_bounds__(256) void vtrans2(const f16* __restrict__ qkvh, f16* __restrict__ vt) {
    __shared__ __align__(16) char Ls[64 * 516];
    int tile = blockIdx.x;
    int st = tile & 31;
    int by = tile >> 5;
    int b = by >> 2, kvh = by & 3;
    int tid = threadIdx.x;
    int s0 = st * 64;
    const f16* src = qkvh + ((size_t)(b * 2048 + s0)) * 4096 + 3072 + kvh * 256;
#pragma unroll
    for (int it = 0; it < 8; ++it) {
        int idx = it * 256 + tid;
        int srow = idx >> 5;
        int col8 = (idx & 31) * 8;
        f16x8 x = *(const f16x8*)(src + (size_t)srow * 4096 + col8);
        char* lp = Ls + srow * 516 + col8 * 2;
        *(f16x2*)(lp)      = f16x2{x[0], x[1]};
        *(f16x2*)(lp + 4)  = f16x2{x[2], x[3]};
        *(f16x2*)(lp + 8)  = f16x2{x[4], x[5]};
        *(f16x2*)(lp + 12) = f16x2{x[6], x[7]};
    }
    __syncthreads();
    f16* dst = vt + ((size_t)(by * 256) * 2048) + s0;
#pragma unroll
    for (int p = 0; p < 8; ++p) {
        int d = p * 32 + (tid >> 3);
        int s8 = (tid & 7) * 8;
        f16x8 o;
#pragma unroll
        for (int j = 0; j < 8; ++j)
            o[j] = *(const f16*)(Ls + (s8 + j) * 516 + d * 2);
        *(f16x8*)(dst + (size_t)d * 2048 + s8) = o;
    }
}

// ============ fused scores+softcap+mask+softmax+probs-write+PV ==============
__global__ __launch_bounds__(256) void attn_fused(const f16* __restrict__ qr, const f16* __restrict__ kr,
                                                  const f16* __restrict__ vt, float* __restrict__ probs,
                                                  f16* __restrict__ attn) {
    int qt = blockIdx.x, bh = blockIdx.y;
    int b = bh >> 3, h = bh & 7;
    int tid = threadIdx.x, lane = tid & 63, w = tid >> 6;
    int g = lane >> 4;
    __shared__ __align__(16) char lds[73728];   // 2x32KB K/V dbuf + 8KB P
    char* plb = lds + 65536;

    const f16* qbase = qr + ((size_t)bh * 2048 + qt * 64 + w * 16 + (lane & 15)) * 256 + g * 8;
    f16x8 af[8];
#pragma unroll
    for (int ks = 0; ks < 8; ++ks) af[ks] = *(const f16x8*)(qbase + ks * 32);

    const int kt_first = (qt >= 8) ? 0 : (8 - qt);
    const f16* kb0 = kr + ((size_t)((b * 4 + (h >> 1)) * 2048)) * 256;

#define KSTAGE(kta_, par_)                                                    \
    {                                                                         \
        const f16* kb_ = kb0 + (size_t)(kta_) * 16384;                        \
        char* db_ = lds + (par_) * 32768;                                     \
        _Pragma("unroll")                                                     \
        for (int is = 0; is < 8; ++is) {                                      \
            int off = is * 4096 + w * 1024 + lane * 16;                       \
            int row = off >> 9;                                               \
            int sb = (off & 511) ^ ((row & 7) << 4);                          \
            gld16(kb_ + row * 256 + (sb >> 1), db_ + off);                    \
        }                                                                     \
    }

    KSTAGE(qt - 8 + kt_first, kt_first & 1)
    f32x4 acc[9][4] = {};
#pragma unroll
    for (int kt = 0; kt < 9; ++kt) {
        int kta = qt - 8 + kt;
        if (kta >= 0) {
            if (kt < 8) {
                KSTAGE(kta + 1, (kt + 1) & 1)
                asm volatile("s_waitcnt vmcnt(8)" ::: "memory");
            } else {
                asm volatile("s_waitcnt vmcnt(0)" ::: "memory");
            }
            __builtin_amdgcn_s_barrier();
            __builtin_amdgcn_sched_barrier(0);
            const char* kbuf = lds + (kt & 1) * 32768;
            __builtin_amdgcn_s_setprio(1);
#pragma unroll
            for (int n = 0; n < 4; ++n) {
                int row2 = n * 16 + (lane & 15);
#pragma unroll
                for (int ks = 0; ks < 8; ++ks) {
                    int cb = (ks * 64 + g * 16) ^ ((row2 & 7) << 4);
                    f16x8 bfr = *(const f16x8*)(kbuf + row2 * 512 + cb);
                    acc[kt][n] = MFMA16(af[ks], bfr, acc[kt][n]);
                }
            }
            __builtin_amdgcn_s_setprio(0);
            __builtin_amdgcn_s_barrier();
        }
    }

    int row_l = w * 16 + (g << 2);
    int row_g0 = qt * 64 + row_l;
    f32x4 mx = {-1e30f, -1e30f, -1e30f, -1e30f};
#pragma unroll
    for (int kt = 0; kt < 9; ++kt) {
        int kta = qt - 8 + kt;
#pragma unroll
        for (int n = 0; n < 4; ++n) {
            int col = kta * 64 + n * 16 + (lane & 15);
#pragma unroll
            for (int r = 0; r < 4; ++r) {
                float s = acc[kt][n][r] * 0.0625f;
                float t = __expf(s * 0.04f);
                float v = 50.0f * (t - 1.0f) / (t + 1.0f);
                int rowg = row_g0 + r;
                bool ok = (kta >= 0) && (col <= rowg) && (rowg - col < 512);
                float pv_ = ok ? v : -1e9f;
                acc[kt][n][r] = pv_;
                mx[r] = fmaxf(mx[r], pv_);
            }
        }
    }
#pragma unroll
    for (int o = 1; o < 16; o <<= 1) {
#pragma unroll
        for (int r = 0; r < 4; ++r) mx[r] = fmaxf(mx[r], __shfl_xor(mx[r], o, 64));
    }
    f32x4 sm = {0.f, 0.f, 0.f, 0.f};
#pragma unroll
    for (int kt = 0; kt < 9; ++kt)
#pragma unroll
        for (int n = 0; n < 4; ++n)
#pragma unroll
            for (int r = 0; r < 4; ++r) {
                float e = __expf(acc[kt][n][r] - mx[r]);
                acc[kt][n][r] = e;
                sm[r] += e;
            }
#pragma unroll
    for (int o = 1; o < 16; o <<= 1) {
#pragma unroll
        for (int r = 0; r < 4; ++r) sm[r] += __shfl_xor(sm[r], o, 64);
    }
    f32x4 inv;
#pragma unroll
    for (int r = 0; r < 4; ++r) inv[r] = 1.0f / sm[r];
    f16x4 ph[9][4];
#pragma unroll
    for (int kt = 0; kt < 9; ++kt)
#pragma unroll
        for (int n = 0; n < 4; ++n)
#pragma unroll
            for (int r = 0; r < 4; ++r)
                ph[kt][n][r] = (f16)(acc[kt][n][r] * inv[r]);

    const f16* vtb = vt + (size_t)((b * 4 + (h >> 1)) * 256) * 2048;

#define VSTAGE(kta_, par_)                                                    \
    {                                                                         \
        char* db_ = lds + (par_) * 32768;                                     \
        _Pragma("unroll")                                                     \
        for (int is = 0; is < 8; ++is) {                                      \
            int off = is * 4096 + w * 1024 + lane * 16;                       \
            int d = off >> 7;                                                 \
            int sb = (off & 127) ^ ((d & 7) << 4);                            \
            gld16(vtb + (size_t)d * 2048 + (kta_) * 64 + (sb >> 1), db_ + off); \
        }                                                                     \
    }

    VSTAGE(qt - 8 + kt_first, kt_first & 1)
    f32x4 pacc[16] = {};
#pragma unroll
    for (int kt = 0; kt < 9; ++kt) {
        int kta = qt - 8 + kt;
        if (kta >= 0) {
            if (kt < 8) VSTAGE(kta + 1, (kt + 1) & 1)
#pragma unroll
            for (int n = 0; n < 4; ++n)
#pragma unroll
                for (int r = 0; r < 4; ++r) {
                    int row = row_l + r;
                    int cb = (n * 16 + (lane & 15)) * 2;
                    *(f16*)(plb + row * 128 + (cb ^ ((row & 7) << 4))) = ph[kt][n][r];
                }
            if (kt < 8) {
                asm volatile("s_waitcnt vmcnt(8) lgkmcnt(0)" ::: "memory");
            } else {
                asm volatile("s_waitcnt vmcnt(0) lgkmcnt(0)" ::: "memory");
            }
            __builtin_amdgcn_s_barrier();
            __builtin_amdgcn_sched_barrier(0);
#pragma unroll
            for (int n = 0; n < 4; ++n) {
                int col = kta * 64 + n * 16 + (lane & 15);
#pragma unroll
                for (int r = 0; r < 4; ++r)
                    probs[((size_t)bh * 2048 + row_g0 + r) * 2048 + col] = (float)ph[kt][n][r];
            }
            const char* vbuf = lds + (kt & 1) * 32768;
            int rowp = w * 16 + (lane & 15);
            int pswz = (rowp & 7) << 4;
            f16x8 a0 = *(const f16x8*)(plb + rowp * 128 + ((g * 16) ^ pswz));
            f16x8 a1 = *(const f16x8*)(plb + rowp * 128 + ((g * 16 + 64) ^ pswz));
            __builtin_amdgcn_s_setprio(1);
#pragma unroll
            for (int n = 0; n < 16; ++n) {
                int d = n * 16 + (lane & 15);
                int vswz = (d & 7) << 4;
                f16x8 b0 = *(const f16x8*)(vbuf + d * 128 + ((g * 16) ^ vswz));
                f16x8 b1 = *(const f16x8*)(vbuf + d * 128 + ((g * 16 + 64) ^ vswz));
                pacc[n] = MFMA16(a0, b0, pacc[n]);
                pacc[n] = MFMA16(a1, b1, pacc[n]);
            }
            __builtin_amdgcn_s_setprio(0);
            __builtin_amdgcn_s_barrier();
        }
    }
#undef KSTAGE
#undef VSTAGE

    int kt0 = qt > 8 ? qt - 8 : 0;
    int pre = kt0 * 64;
    int suf = (qt + 1) * 64;
    float4 z4 = make_float4(0.f, 0.f, 0.f, 0.f);
    for (int r = 0; r < 16; ++r) {
        float* rp = probs + ((size_t)bh * 2048 + qt * 64 + w * 16 + r) * 2048;
        for (int off = lane * 4; off < pre; off += 256) *(float4*)(rp + off) = z4;
        for (int off = suf + lane * 4; off < 2048; off += 256) *(float4*)(rp + off) = z4;
    }

    size_t obase = ((size_t)b * 2048 + qt * 64 + row_l) * 2048 + h * 256;
#pragma unroll
    for (int n = 0; n < 16; ++n) {
        int col = n * 16 + (lane & 15);
#pragma unroll
        for (int r = 0; r < 4; ++r)
            attn[obase + (size_t)r * 2048 + col] = (f16)pacc[n][r];
    }
}

extern "C" void kernel_launch(void* const* d_in, const int* in_sizes, int n_in,
                              void* d_out, int out_size, void* d_ws, size_t ws_size,
                              hipStream_t stream) {
    (void)in_sizes; (void)n_in; (void)out_size; (void)ws_size;
    const float* hs   = (const float*)d_in[0];
    const float* cosb = (const float*)d_in[1];
    const float* sinb = (const float*)d_in[2];
    const float* qw   = (const float*)d_in[4];
    const float* kw   = (const float*)d_in[5];
    const float* vw   = (const float*)d_in[6];
    const float* ow   = (const float*)d_in[7];
    const float* qnw  = (const float*)d_in[8];
    const float* knw  = (const float*)d_in[9];

    float* out = (float*)d_out;
    float* probs = out + (size_t)2 * 2048 * 2560;          // output 1

    char* ws = (char*)d_ws;
    f16* hsb  = (f16*)(ws);                                // 20,971,520 B
    f16* wqkv = (f16*)(ws + 20971520);                     // 20,971,520 B
    f16* owb  = (f16*)(ws + 41943040);                     // 10,485,760 B
    f16* qkvh = (f16*)(ws + 52428800);                     // 33,554,432 B
    f16* qr   = (f16*)(ws + 85983232);                     // 16,777,216 B
    f16* kr   = (f16*)(ws + 102760448);                    //  8,388,608 B
    f16* vt   = (f16*)(ws + 111149056);                    //  8,388,608 B
    f16* attn = (f16*)(ws + 119537664);                    // 16,777,216 B

    // all fp32 -> fp16 casts in one launch
    cvt_all<<<12800, 256, 0, stream>>>(hs, qw, kw, vw, ow, hsb, wqkv, owb);

    // fused QKV projection: 256^2 BK=64 single-barrier pipeline, f16 out
    gemm256<2560, 4096, 16, true><<<256, 512, 0, stream>>>(hsb, wqkv, qkvh);

    // RMSNorm + RoPE; V transpose (LDS-tiled)
    rmsrope_k<<<12288, 256, 0, stream>>>(qkvh, cosb, sinb, qnw, knw, qr, kr);
    vtrans2<<<256, 256, 0, stream>>>(qkvh, vt);

    // fused scores+softmax+probs+PV (dbuf K/V, counted vmcnt)
    attn_fused<<<dim3(32, 16), 256, 0, stream>>>(qr, kr, vt, probs, attn);

    // O projection: 256^2 BK=64 single-barrier pipeline, f32 out (output 0)
    gemm256<2048, 2560, 10, false><<<160, 512, 0, stream>>>(attn, owb, out);
}

// Round 10
// 276.057 us; speedup vs baseline: 1.5925x; 1.1707x over previous
//
#include <hip/hip_runtime.h>

typedef _Float16 f16;
typedef float f32x4 __attribute__((ext_vector_type(4)));
typedef _Float16 f16x8 __attribute__((ext_vector_type(8)));
typedef _Float16 f16x4 __attribute__((ext_vector_type(4)));
typedef _Float16 f16x2 __attribute__((ext_vector_type(2)));

#define MFMA16(a, b, c) __builtin_amdgcn_mfma_f32_16x16x32_f16((a), (b), (c), 0, 0, 0)

__device__ __forceinline__ void gld16(const void* g, void* l) {
    __builtin_amdgcn_global_load_lds((const __attribute__((address_space(1))) unsigned int*)g,
                                     (__attribute__((address_space(3))) unsigned int*)l, 16, 0, 0);
}

// ---------------- merged fp32 -> fp16 cast for all 5 tensors ----------------
__global__ __launch_bounds__(256) void cvt_all(const float* __restrict__ hs, const float* __restrict__ qw,
                                               const float* __restrict__ kw, const float* __restrict__ vw,
                                               const float* __restrict__ ow, f16* __restrict__ hsb,
                                               f16* __restrict__ wqkv, f16* __restrict__ owb) {
    long g = (long)(blockIdx.x * 256 + threadIdx.x) * 8;
    const float* src;
    f16* dst;
    long off;
    if (g < 10485760L) { src = hs; dst = hsb; off = g; }
    else if (g < 15728640L) { src = qw; dst = wqkv; off = g - 10485760L; }
    else if (g < 18350080L) { src = kw; dst = wqkv + 5242880; off = g - 15728640L; }
    else if (g < 20971520L) { src = vw; dst = wqkv + 7864320; off = g - 18350080L; }
    else { src = ow; dst = owb; off = g - 20971520L; }
    float4 a = *(const float4*)(src + off);
    float4 b = *(const float4*)(src + off + 4);
    f16x8 o;
    o[0] = (f16)a.x; o[1] = (f16)a.y; o[2] = (f16)a.z; o[3] = (f16)a.w;
    o[4] = (f16)b.x; o[5] = (f16)b.y; o[6] = (f16)b.z; o[7] = (f16)b.w;
    *(f16x8*)(dst + off) = o;
}

// ============ 256x256-tile GEMM, BK=64, 2-buf, 1 barrier/K-tile (T1-T5) =====
template <int K, int N, int GN, bool F16OUT>
__global__ __launch_bounds__(512, 1) void gemm256(const f16* __restrict__ A, const f16* __restrict__ W,
                                                  void* __restrict__ Cv) {
    constexpr int NT = K / 64;
    __shared__ __align__(16) char lds[131072];
    const int tid = threadIdx.x;
    const int lane = tid & 63, wid = tid >> 6;
    const int wr = wid >> 2, wc = wid & 3;
    const int g = lane >> 4;
    int bid = blockIdx.x;
    int swz = (bid & 7) * ((16 * GN) >> 3) + (bid >> 3);
    const int m0 = (swz / GN) * 256, n0 = (swz % GN) * 256;

    const int kel = 8 * ((tid & 7) ^ ((tid >> 3) & 7));   // pre-swizzled k (elems)
    const int rowb = tid >> 3;                            // 0..63
    const f16* pA = A + (size_t)(m0 + rowb) * K + kel;
    const f16* pB = W + (size_t)(n0 + rowb) * K + kel;
    const int dst_o = tid * 16;

#define QSTAGE(bi, t)                                                     \
    {                                                                     \
        char* lb_ = lds + (bi) * 65536;                                   \
        int k0_ = (t) * 64;                                               \
        gld16(pA + k0_,                 lb_ + dst_o);                     \
        gld16(pA + (size_t)64 * K + k0_,  lb_ + 8192 + dst_o);            \
        gld16(pA + (size_t)128 * K + k0_, lb_ + 16384 + dst_o);           \
        gld16(pA + (size_t)192 * K + k0_, lb_ + 24576 + dst_o);           \
        gld16(pB + k0_,                 lb_ + 32768 + dst_o);             \
        gld16(pB + (size_t)64 * K + k0_,  lb_ + 40960 + dst_o);           \
        gld16(pB + (size_t)128 * K + k0_, lb_ + 49152 + dst_o);           \
        gld16(pB + (size_t)192 * K + k0_, lb_ + 57344 + dst_o);           \
    }

    const int xorv = (lane & 7) << 4;
    const int arow = wr * 128 + (lane & 15);
    const int brow = wc * 64 + (lane & 15);

    f32x4 acc[8][4] = {};

#define QCOMPUTE(bi)                                                      \
    {                                                                     \
        const char* ab_ = lds + (bi) * 65536;                             \
        const char* bb_ = ab_ + 32768;                                    \
        _Pragma("unroll")                                                 \
        for (int ks = 0; ks < 2; ++ks) {                                  \
            const int cc = (ks * 64 + g * 16) ^ xorv;                     \
            f16x8 Af[8], Bf[4];                                           \
            _Pragma("unroll")                                             \
            for (int m = 0; m < 8; ++m)                                   \
                Af[m] = *(const f16x8*)(ab_ + (arow + m * 16) * 128 + cc);\
            _Pragma("unroll")                                             \
            for (int n = 0; n < 4; ++n)                                   \
                Bf[n] = *(const f16x8*)(bb_ + (brow + n * 16) * 128 + cc);\
            __builtin_amdgcn_s_setprio(1);                                \
            _Pragma("unroll")                                             \
            for (int m = 0; m < 8; ++m)                                   \
                _Pragma("unroll")                                         \
                for (int n = 0; n < 4; ++n)                               \
                    acc[m][n] = MFMA16(Af[m], Bf[n], acc[m][n]);          \
            __builtin_amdgcn_s_setprio(0);                                \
        }                                                                 \
    }

    QSTAGE(0, 0)
    asm volatile("s_waitcnt vmcnt(0)" ::: "memory");
    __builtin_amdgcn_s_barrier();

#pragma unroll 1
    for (int t = 0; t < NT; ++t) {
        if (t + 1 < NT) QSTAGE((t + 1) & 1, t + 1)   // issue-early (T14/T3)
        QCOMPUTE(t & 1)
        asm volatile("s_waitcnt vmcnt(0) lgkmcnt(0)" ::: "memory");
        __builtin_amdgcn_s_barrier();                // one barrier per K-tile
    }

#pragma unroll
    for (int m = 0; m < 8; ++m) {
        int row = m0 + wr * 128 + m * 16 + ((lane >> 4) << 2);
#pragma unroll
        for (int n = 0; n < 4; ++n) {
            int col = n0 + wc * 64 + n * 16 + (lane & 15);
#pragma unroll
            for (int r = 0; r < 4; ++r) {
                if constexpr (F16OUT)
                    ((f16*)Cv)[(size_t)(row + r) * N + col] = (f16)acc[m][n][r];
                else
                    __builtin_nontemporal_store(acc[m][n][r],
                        &((float*)Cv)[(size_t)(row + r) * N + col]);
            }
        }
    }
#undef QSTAGE
#undef QCOMPUTE
}

// ------- merged RMSNorm+RoPE (blocks 0..12287) + V transpose (12288..12543) -
__global__ __launch_bounds__(256) void rmsvt_k(const f16* __restrict__ qkvh,
                                               const float* __restrict__ cosb, const float* __restrict__ sinb,
                                               const float* __restrict__ qnw, const float* __restrict__ knw,
                                               f16* __restrict__ qr, f16* __restrict__ kr,
                                               f16* __restrict__ vt) {
    if (blockIdx.x < 12288) {
        // ---- RMSNorm + RoPE: one wave per (b,s,head) ----
        int wid = threadIdx.x >> 6, lane = threadIdx.x & 63;
        int task = blockIdx.x * 4 + wid;
        int slot = task % 12;
        int bs = task / 12;
        int b = bs >> 11, s = bs & 2047;
        const f16* src;
        const float* w;
        f16* dst;
        if (slot < 8) {
            src = qkvh + (size_t)bs * 4096 + slot * 256;
            w = qnw;
            dst = qr + ((size_t)(b * 8 + slot) * 2048 + s) * 256;
        } else {
            int h = slot - 8;
            src = qkvh + (size_t)bs * 4096 + 2048 + h * 256;
            w = knw;
            dst = kr + ((size_t)(b * 4 + h) * 2048 + s) * 256;
        }
        int i = lane * 4;
        f16x4 xr = *(const f16x4*)(src + i);
        float4 x;
        x.x = (float)xr[0]; x.y = (float)xr[1]; x.z = (float)xr[2]; x.w = (float)xr[3];
        float ss = x.x * x.x + x.y * x.y + x.z * x.z + x.w * x.w;
#pragma unroll
        for (int o = 32; o; o >>= 1) ss += __shfl_xor(ss, o, 64);
        float rs = rsqrtf(ss * (1.0f / 256.0f) + 1e-6f);
        float4 y;
        y.x = __shfl_xor(x.x, 32, 64);
        y.y = __shfl_xor(x.y, 32, 64);
        y.z = __shfl_xor(x.z, 32, 64);
        y.w = __shfl_xor(x.w, 32, 64);
        float4 wv = *(const float4*)(w + i);
        float4 wp = *(const float4*)(w + (i ^ 128));
        float4 c = *(const float4*)(cosb + (size_t)bs * 256 + i);
        float4 sn = *(const float4*)(sinb + (size_t)bs * 256 + i);
        float sgn = (lane < 32) ? -1.0f : 1.0f;
        float n0 = x.x * rs * (1.f + wv.x), n1 = x.y * rs * (1.f + wv.y);
        float n2 = x.z * rs * (1.f + wv.z), n3 = x.w * rs * (1.f + wv.w);
        float r0 = y.x * rs * (1.f + wp.x) * sgn, r1 = y.y * rs * (1.f + wp.y) * sgn;
        float r2 = y.z * rs * (1.f + wp.z) * sgn, r3 = y.w * rs * (1.f + wp.w) * sgn;
        f16x4 outv;
        outv[0] = (f16)(n0 * c.x + r0 * sn.x);
        outv[1] = (f16)(n1 * c.y + r1 * sn.y);
        outv[2] = (f16)(n2 * c.z + r2 * sn.z);
        outv[3] = (f16)(n3 * c.w + r3 * sn.w);
        *(f16x4*)(dst + i) = outv;
    } else {
        // ---- V transpose tile ----
        __shared__ __align__(16) char Ls[64 * 516];
        int tile = blockIdx.x - 12288;   // 0..255
        int st = tile & 31;
        int by = tile >> 5;
        int b = by >> 2, kvh = by & 3;
        int tid = threadIdx.x;
        int s0 = st * 64;
        const f16* src = qkvh + ((size_t)(b * 2048 + s0)) * 4096 + 3072 + kvh * 256;
#pragma unroll
        for (int it = 0; it < 8; ++it) {
            int idx = it * 256 + tid;
            int srow = idx >> 5;
            int col8 = (idx & 31) * 8;
            f16x8 x = *(const f16x8*)(src + (size_t)srow * 4096 + col8);
            char* lp = Ls + srow * 516 + col8 * 2;
            *(f16x2*)(lp)      = f16x2{x[0], x[1]};
            *(f16x2*)(lp + 4)  = f16x2{x[2], x[3]};
            *(f16x2*)(lp + 8)  = f16x2{x[4], x[5]};
            *(f16x2*)(lp + 12) = f16x2{x[6], x[7]};
        }
        __syncthreads();
        f16* dst = vt + ((size_t)(by * 256) * 2048) + s0;
#pragma unroll
        for (int p = 0; p < 8; ++p) {
            int d = p * 32 + (tid >> 3);
            int s8 = (tid & 7) * 8;
            f16x8 o;
#pragma unroll
            for (int j = 0; j < 8; ++j)
                o[j] = *(const f16*)(Ls + (s8 + j) * 516 + d * 2);
            *(f16x8*)(dst + (size_t)d * 2048 + s8) = o;
        }
    }
}

// ============ fused scores+softcap+mask+softmax+probs-write+PV ==============
__global__ __launch_bounds__(256) void attn_fused(const f16* __restrict__ qr, const f16* __restrict__ kr,
                                                  const f16* __restrict__ vt, float* __restrict__ probs,
                                                  f16* __restrict__ attn) {
    int qt = blockIdx.x, bh = blockIdx.y;
    int b = bh >> 3, h = bh & 7;
    int tid = threadIdx.x, lane = tid & 63, w = tid >> 6;
    int g = lane >> 4;
    __shared__ __align__(16) char lds[73728];   // 2x32KB K/V dbuf + 8KB P
    char* plb = lds + 65536;

    const f16* qbase = qr + ((size_t)bh * 2048 + qt * 64 + w * 16 + (lane & 15)) * 256 + g * 8;
    f16x8 af[8];
#pragma unroll
    for (int ks = 0; ks < 8; ++ks) af[ks] = *(const f16x8*)(qbase + ks * 32);

    const int kt_first = (qt >= 8) ? 0 : (8 - qt);
    const f16* kb0 = kr + ((size_t)((b * 4 + (h >> 1)) * 2048)) * 256;

#define KSTAGE(kta_, par_)                                                    \
    {                                                                         \
        const f16* kb_ = kb0 + (size_t)(kta_) * 16384;                        \
        char* db_ = lds + (par_) * 32768;                                     \
        _Pragma("unroll")                                                     \
        for (int is = 0; is < 8; ++is) {                                      \
            int off = is * 4096 + w * 1024 + lane * 16;                       \
            int row = off >> 9;                                               \
            int sb = (off & 511) ^ ((row & 7) << 4);                          \
            gld16(kb_ + row * 256 + (sb >> 1), db_ + off);                    \
        }                                                                     \
    }

    KSTAGE(qt - 8 + kt_first, kt_first & 1)
    f32x4 acc[9][4] = {};
#pragma unroll
    for (int kt = 0; kt < 9; ++kt) {
        int kta = qt - 8 + kt;
        if (kta >= 0) {
            if (kt < 8) {
                KSTAGE(kta + 1, (kt + 1) & 1)
                asm volatile("s_waitcnt vmcnt(8)" ::: "memory");
            } else {
                asm volatile("s_waitcnt vmcnt(0)" ::: "memory");
            }
            __builtin_amdgcn_s_barrier();
            __builtin_amdgcn_sched_barrier(0);
            const char* kbuf = lds + (kt & 1) * 32768;
            __builtin_amdgcn_s_setprio(1);
#pragma unroll
            for (int n = 0; n < 4; ++n) {
                int row2 = n * 16 + (lane & 15);
#pragma unroll
                for (int ks = 0; ks < 8; ++ks) {
                    int cb = (ks * 64 + g * 16) ^ ((row2 & 7) << 4);
                    f16x8 bfr = *(const f16x8*)(kbuf + row2 * 512 + cb);
                    acc[kt][n] = MFMA16(af[ks], bfr, acc[kt][n]);
                }
            }
            __builtin_amdgcn_s_setprio(0);
            __builtin_amdgcn_s_barrier();
        }
    }

    int row_l = w * 16 + (g << 2);
    int row_g0 = qt * 64 + row_l;
    f32x4 mx = {-1e30f, -1e30f, -1e30f, -1e30f};
#pragma unroll
    for (int kt = 0; kt < 9; ++kt) {
        int kta = qt - 8 + kt;
#pragma unroll
        for (int n = 0; n < 4; ++n) {
            int col = kta * 64 + n * 16 + (lane & 15);
#pragma unroll
            for (int r = 0; r < 4; ++r) {
                float s = acc[kt][n][r] * 0.0625f;
                float t = __expf(s * 0.04f);
                float v = 50.0f * (t - 1.0f) / (t + 1.0f);
                int rowg = row_g0 + r;
                bool ok = (kta >= 0) && (col <= rowg) && (rowg - col < 512);
                float pv_ = ok ? v : -1e9f;
                acc[kt][n][r] = pv_;
                mx[r] = fmaxf(mx[r], pv_);
            }
        }
    }
#pragma unroll
    for (int o = 1; o < 16; o <<= 1) {
#pragma unroll
        for (int r = 0; r < 4; ++r) mx[r] = fmaxf(mx[r], __shfl_xor(mx[r], o, 64));
    }
    f32x4 sm = {0.f, 0.f, 0.f, 0.f};
#pragma unroll
    for (int kt = 0; kt < 9; ++kt)
#pragma unroll
        for (int n = 0; n < 4; ++n)
#pragma unroll
            for (int r = 0; r < 4; ++r) {
                float e = __expf(acc[kt][n][r] - mx[r]);
                acc[kt][n][r] = e;
                sm[r] += e;
            }
#pragma unroll
    for (int o = 1; o < 16; o <<= 1) {
#pragma unroll
        for (int r = 0; r < 4; ++r) sm[r] += __shfl_xor(sm[r], o, 64);
    }
    f32x4 inv;
#pragma unroll
    for (int r = 0; r < 4; ++r) inv[r] = 1.0f / sm[r];
    f16x4 ph[9][4];
#pragma unroll
    for (int kt = 0; kt < 9; ++kt)
#pragma unroll
        for (int n = 0; n < 4; ++n)
#pragma unroll
            for (int r = 0; r < 4; ++r)
                ph[kt][n][r] = (f16)(acc[kt][n][r] * inv[r]);

    const f16* vtb = vt + (size_t)((b * 4 + (h >> 1)) * 256) * 2048;

#define VSTAGE(kta_, par_)                                                    \
    {                                                                         \
        char* db_ = lds + (par_) * 32768;                                     \
        _Pragma("unroll")                                                     \
        for (int is = 0; is < 8; ++is) {                                      \
            int off = is * 4096 + w * 1024 + lane * 16;                       \
            int d = off >> 7;                                                 \
            int sb = (off & 127) ^ ((d & 7) << 4);                            \
            gld16(vtb + (size_t)d * 2048 + (kta_) * 64 + (sb >> 1), db_ + off); \
        }                                                                     \
    }

    VSTAGE(qt - 8 + kt_first, kt_first & 1)
    f32x4 pacc[16] = {};
#pragma unroll
    for (int kt = 0; kt < 9; ++kt) {
        int kta = qt - 8 + kt;
        if (kta >= 0) {
            if (kt < 8) VSTAGE(kta + 1, (kt + 1) & 1)
#pragma unroll
            for (int n = 0; n < 4; ++n)
#pragma unroll
                for (int r = 0; r < 4; ++r) {
                    int row = row_l + r;
                    int cb = (n * 16 + (lane & 15)) * 2;
                    *(f16*)(plb + row * 128 + (cb ^ ((row & 7) << 4))) = ph[kt][n][r];
                }
            if (kt < 8) {
                asm volatile("s_waitcnt vmcnt(8) lgkmcnt(0)" ::: "memory");
            } else {
                asm volatile("s_waitcnt vmcnt(0) lgkmcnt(0)" ::: "memory");
            }
            __builtin_amdgcn_s_barrier();
            __builtin_amdgcn_sched_barrier(0);
            // probs band stores — non-temporal (write-once, drain under MFMA)
#pragma unroll
            for (int n = 0; n < 4; ++n) {
                int col = kta * 64 + n * 16 + (lane & 15);
#pragma unroll
                for (int r = 0; r < 4; ++r)
                    __builtin_nontemporal_store((float)ph[kt][n][r],
                        &probs[((size_t)bh * 2048 + row_g0 + r) * 2048 + col]);
            }
            const char* vbuf = lds + (kt & 1) * 32768;
            int rowp = w * 16 + (lane & 15);
            int pswz = (rowp & 7) << 4;
            f16x8 a0 = *(const f16x8*)(plb + rowp * 128 + ((g * 16) ^ pswz));
            f16x8 a1 = *(const f16x8*)(plb + rowp * 128 + ((g * 16 + 64) ^ pswz));
            __builtin_amdgcn_s_setprio(1);
#pragma unroll
            for (int n = 0; n < 16; ++n) {
                int d = n * 16 + (lane & 15);
                int vswz = (d & 7) << 4;
                f16x8 b0 = *(const f16x8*)(vbuf + d * 128 + ((g * 16) ^ vswz));
                f16x8 b1 = *(const f16x8*)(vbuf + d * 128 + ((g * 16 + 64) ^ vswz));
                pacc[n] = MFMA16(a0, b0, pacc[n]);
                pacc[n] = MFMA16(a1, b1, pacc[n]);
            }
            __builtin_amdgcn_s_setprio(0);
            __builtin_amdgcn_s_barrier();
        }
    }
#undef KSTAGE
#undef VSTAGE

    int kt0 = qt > 8 ? qt - 8 : 0;
    int pre = kt0 * 64;
    int suf = (qt + 1) * 64;
    f32x4 z4 = {0.f, 0.f, 0.f, 0.f};
    for (int r = 0; r < 16; ++r) {
        float* rp = probs + ((size_t)bh * 2048 + qt * 64 + w * 16 + r) * 2048;
        for (int off = lane * 4; off < pre; off += 256)
            __builtin_nontemporal_store(z4, (f32x4*)(rp + off));
        for (int off = suf + lane * 4; off < 2048; off += 256)
            __builtin_nontemporal_store(z4, (f32x4*)(rp + off));
    }

    size_t obase = ((size_t)b * 2048 + qt * 64 + row_l) * 2048 + h * 256;
#pragma unroll
    for (int n = 0; n < 16; ++n) {
        int col = n * 16 + (lane & 15);
#pragma unroll
        for (int r = 0; r < 4; ++r)
            attn[obase + (size_t)r * 2048 + col] = (f16)pacc[n][r];
    }
}

extern "C" void kernel_launch(void* const* d_in, const int* in_sizes, int n_in,
                              void* d_out, int out_size, void* d_ws, size_t ws_size,
                              hipStream_t stream) {
    (void)in_sizes; (void)n_in; (void)out_size; (void)ws_size;
    const float* hs   = (const float*)d_in[0];
    const float* cosb = (const float*)d_in[1];
    const float* sinb = (const float*)d_in[2];
    const float* qw   = (const float*)d_in[4];
    const float* kw   = (const float*)d_in[5];
    const float* vw   = (const float*)d_in[6];
    const float* ow   = (const float*)d_in[7];
    const float* qnw  = (const float*)d_in[8];
    const float* knw  = (const float*)d_in[9];

    float* out = (float*)d_out;
    float* probs = out + (size_t)2 * 2048 * 2560;          // output 1

    char* ws = (char*)d_ws;
    f16* hsb  = (f16*)(ws);                                // 20,971,520 B
    f16* wqkv = (f16*)(ws + 20971520);                     // 20,971,520 B
    f16* owb  = (f16*)(ws + 41943040);                     // 10,485,760 B
    f16* qkvh = (f16*)(ws + 52428800);                     // 33,554,432 B
    f16* qr   = (f16*)(ws + 85983232);                     // 16,777,216 B
    f16* kr   = (f16*)(ws + 102760448);                    //  8,388,608 B
    f16* vt   = (f16*)(ws + 111149056);                    //  8,388,608 B
    f16* attn = (f16*)(ws + 119537664);                    // 16,777,216 B

    // all fp32 -> fp16 casts in one launch
    cvt_all<<<12800, 256, 0, stream>>>(hs, qw, kw, vw, ow, hsb, wqkv, owb);

    // fused QKV projection: 256^2 BK=64 single-barrier pipeline, f16 out
    gemm256<2560, 4096, 16, true><<<256, 512, 0, stream>>>(hsb, wqkv, qkvh);

    // merged RMSNorm+RoPE + V transpose (one launch)
    rmsvt_k<<<12544, 256, 0, stream>>>(qkvh, cosb, sinb, qnw, knw, qr, kr, vt);

    // fused scores+softmax+probs+PV (dbuf K/V, counted vmcnt, NT probs stores)
    attn_fused<<<dim3(32, 16), 256, 0, stream>>>(qr, kr, vt, probs, attn);

    // O projection: 256^2 BK=64 single-barrier pipeline, NT f32 out (output 0)
    gemm256<2048, 2560, 10, false><<<160, 512, 0, stream>>>(attn, owb, out);
}